// Round 1
// baseline (1731.435 us; speedup 1.0000x reference)
//
#include <hip/hip_runtime.h>
#include <hip/hip_bf16.h>
#include <math.h>

typedef unsigned short u16;
typedef __attribute__((ext_vector_type(8))) short bf16x8;
typedef __attribute__((ext_vector_type(4))) float f32x4;

__device__ __forceinline__ u16 f2b(float f) {
    union { float f; unsigned u; } v; v.f = f;
    unsigned r = v.u + 0x7fffu + ((v.u >> 16) & 1u);
    return (u16)(r >> 16);
}
__device__ __forceinline__ float b2f(u16 h) {
    union { unsigned u; float f; } v; v.u = ((unsigned)h) << 16; return v.f;
}

// ---------------------------------------------------------------------------
// Generic bf16 MFMA GEMM:  C = alpha * A @ Bt^T (+bias) (+res)
// A: M x K row-major (lda), Bt: N x K row-major (ldb)  [i.e. B pre-transposed]
// Batched over grid.z with independent (b,h) offsets per tensor.
// ---------------------------------------------------------------------------
struct GemmP {
    const u16* A; const u16* B;
    const float* bias; const float* res;
    float* Cf; u16* Cb;
    int M, N, K, lda, ldb, ldc;
    int NH, zbA, zbB, zbC;
    long sAb, sAh, sBb, sBh, sCb, sCh;
    float alpha;
};

__global__ __launch_bounds__(256) void gemm_bt(GemmP p) {
    __shared__ u16 As[128 * 40];
    __shared__ u16 Bs[128 * 40];
    const int tid = threadIdx.x;
    const int z = blockIdx.z;
    long offA, offB, offC;
    { int zz = p.zbA + z; offA = (long)(zz / p.NH) * p.sAb + (long)(zz % p.NH) * p.sAh; }
    { int zz = p.zbB + z; offB = (long)(zz / p.NH) * p.sBb + (long)(zz % p.NH) * p.sBh; }
    { int zz = p.zbC + z; offC = (long)(zz / p.NH) * p.sCb + (long)(zz % p.NH) * p.sCh; }
    const u16* A = p.A + offA;
    const u16* B = p.B + offB;
    const int m0 = blockIdx.y * 128, n0 = blockIdx.x * 128;
    const int lane = tid & 63, wave = tid >> 6;
    const int quad = lane >> 4, l16 = lane & 15;
    const int wr = (wave >> 1) * 64, wc = (wave & 1) * 64;
    const int sr = tid >> 1, sc = (tid & 1) * 16;

    f32x4 acc[4][4];
#pragma unroll
    for (int i = 0; i < 4; i++)
#pragma unroll
        for (int j = 0; j < 4; j++) acc[i][j] = (f32x4){0.f, 0.f, 0.f, 0.f};

    for (int k0 = 0; k0 < p.K; k0 += 32) {
        // stage A tile (128 x 32)
        {
            int gm = m0 + sr;
            uint4 v0 = {0,0,0,0}, v1 = {0,0,0,0};
            if (gm < p.M) {
                const u16* src = A + (long)gm * p.lda + k0 + sc;
                if (((p.lda & 7) == 0) && (k0 + sc + 16 <= p.K)) {
                    v0 = *(const uint4*)src;
                    v1 = *(const uint4*)(src + 8);
                } else {
                    u16 tmp[16];
#pragma unroll
                    for (int i = 0; i < 16; i++) tmp[i] = (k0 + sc + i < p.K) ? src[i] : (u16)0;
                    v0 = *(uint4*)tmp; v1 = *(uint4*)(tmp + 8);
                }
            }
            *(uint4*)&As[sr * 40 + sc] = v0;
            *(uint4*)&As[sr * 40 + sc + 8] = v1;
        }
        // stage B tile (128 x 32) from Bt (N x K)
        {
            int gn = n0 + sr;
            uint4 v0 = {0,0,0,0}, v1 = {0,0,0,0};
            if (gn < p.N) {
                const u16* src = B + (long)gn * p.ldb + k0 + sc;
                if (((p.ldb & 7) == 0) && (k0 + sc + 16 <= p.K)) {
                    v0 = *(const uint4*)src;
                    v1 = *(const uint4*)(src + 8);
                } else {
                    u16 tmp[16];
#pragma unroll
                    for (int i = 0; i < 16; i++) tmp[i] = (k0 + sc + i < p.K) ? src[i] : (u16)0;
                    v0 = *(uint4*)tmp; v1 = *(uint4*)(tmp + 8);
                }
            }
            *(uint4*)&Bs[sr * 40 + sc] = v0;
            *(uint4*)&Bs[sr * 40 + sc + 8] = v1;
        }
        __syncthreads();

        bf16x8 af[4], bfr[4];
#pragma unroll
        for (int mi = 0; mi < 4; mi++)
            af[mi] = *(const bf16x8*)&As[(wr + mi * 16 + l16) * 40 + quad * 8];
#pragma unroll
        for (int ni = 0; ni < 4; ni++)
            bfr[ni] = *(const bf16x8*)&Bs[(wc + ni * 16 + l16) * 40 + quad * 8];
#pragma unroll
        for (int mi = 0; mi < 4; mi++)
#pragma unroll
            for (int ni = 0; ni < 4; ni++)
                acc[mi][ni] = __builtin_amdgcn_mfma_f32_16x16x32_bf16(af[mi], bfr[ni], acc[mi][ni], 0, 0, 0);
        __syncthreads();
    }

    // epilogue: D col = lane&15, row = quad*4 + reg
#pragma unroll
    for (int mi = 0; mi < 4; mi++) {
#pragma unroll
        for (int ni = 0; ni < 4; ni++) {
#pragma unroll
            for (int r = 0; r < 4; r++) {
                int row = m0 + wr + mi * 16 + quad * 4 + r;
                int col = n0 + wc + ni * 16 + l16;
                if (row < p.M && col < p.N) {
                    float v = acc[mi][ni][r] * p.alpha;
                    if (p.bias) v += p.bias[col];
                    long idx = offC + (long)row * p.ldc + col;
                    if (p.res) v += p.res[idx];
                    if (p.Cf) p.Cf[idx] = v; else p.Cb[idx] = f2b(v);
                }
            }
        }
    }
}

// ---------------------------------------------------------------------------
// Weight transpose + f32->bf16:  W (K x N) -> Wt (N x K)
// ---------------------------------------------------------------------------
__global__ void wtrans(const float* __restrict__ W, u16* __restrict__ Wt, int K, int N) {
    __shared__ float tile[32][33];
    int n0 = blockIdx.x * 32, k0 = blockIdx.y * 32;
    int tx = threadIdx.x, ty = threadIdx.y;
#pragma unroll
    for (int i = 0; i < 4; i++) {
        int k = k0 + ty + i * 8, n = n0 + tx;
        if (k < K && n < N) tile[ty + i * 8][tx] = W[(long)k * N + n];
    }
    __syncthreads();
#pragma unroll
    for (int i = 0; i < 4; i++) {
        int n = n0 + ty + i * 8, k = k0 + tx;
        if (n < N && k < K) Wt[(long)n * K + k] = f2b(tile[tx][ty + i * 8]);
    }
}

// ---------------------------------------------------------------------------
// GroupNorm: stats (per b,g over 32*32*20 elems) + apply
// ---------------------------------------------------------------------------
__global__ void gn_stats(const float* __restrict__ x, float* __restrict__ stats) {
    int bid = blockIdx.x;          // 0..255 : b*32+g
    int b = bid >> 5, g = bid & 31;
    const float* base = x + (long)b * 32 * 32 * 640 + g * 20;
    float s = 0.f, sq = 0.f;
    for (int idx = threadIdx.x; idx < 32 * 32 * 20; idx += 256) {
        int hw = idx / 20, c = idx - hw * 20;
        float v = base[(long)hw * 640 + c];
        s += v; sq += v * v;
    }
    __shared__ float rs[256], rq[256];
    rs[threadIdx.x] = s; rq[threadIdx.x] = sq; __syncthreads();
    for (int t = 128; t > 0; t >>= 1) {
        if (threadIdx.x < t) { rs[threadIdx.x] += rs[threadIdx.x + t]; rq[threadIdx.x] += rq[threadIdx.x + t]; }
        __syncthreads();
    }
    if (threadIdx.x == 0) {
        float mean = rs[0] / 20480.0f;
        float var = rq[0] / 20480.0f - mean * mean;
        stats[bid * 2] = mean;
        stats[bid * 2 + 1] = rsqrtf(var + 1e-5f);
    }
}

__global__ void gn_apply(const float* __restrict__ x, const float* __restrict__ stats,
                         const float* __restrict__ gamma, const float* __restrict__ beta,
                         u16* __restrict__ out) {
    long i = (long)blockIdx.x * 256 + threadIdx.x;   // total 5242880 exact
    int c = (int)(i % 640);
    int b = (int)(i / (32 * 32 * 640));
    int g = c / 20;
    float mean = stats[(b * 32 + g) * 2], inv = stats[(b * 32 + g) * 2 + 1];
    out[i] = f2b((x[i] - mean) * inv * gamma[c] + beta[c]);
}

// ---------------------------------------------------------------------------
// LayerNorm over 640, one wave per row, bf16 out
// ---------------------------------------------------------------------------
__global__ void layernorm_rows(const float* __restrict__ X, const float* __restrict__ g,
                               const float* __restrict__ be, u16* __restrict__ out, int nrows) {
    int row = blockIdx.x * 4 + (threadIdx.x >> 6);
    int lane = threadIdx.x & 63;
    if (row >= nrows) return;
    const float* x = X + (long)row * 640;
    float v[10];
    float s = 0.f;
#pragma unroll
    for (int i = 0; i < 10; i++) { v[i] = x[lane + i * 64]; s += v[i]; }
#pragma unroll
    for (int m = 1; m < 64; m <<= 1) s += __shfl_xor(s, m);
    float mean = s * (1.0f / 640.0f);
    float sq = 0.f;
#pragma unroll
    for (int i = 0; i < 10; i++) { float d = v[i] - mean; sq += d * d; }
#pragma unroll
    for (int m = 1; m < 64; m <<= 1) sq += __shfl_xor(sq, m);
    float inv = rsqrtf(sq * (1.0f / 640.0f) + 1e-5f);
    u16* o = out + (long)row * 640;
#pragma unroll
    for (int i = 0; i < 10; i++) {
        int c = lane + i * 64;
        o[c] = f2b((v[i] - mean) * inv * g[c] + be[c]);
    }
}

// ---------------------------------------------------------------------------
// Per-head V transpose: vsrc (b*S, 640) head h cols -> Vt[z][d][s], z=b*8+h
// ---------------------------------------------------------------------------
__global__ void transpose_v(const u16* __restrict__ vsrc, u16* __restrict__ Vt, int S, int ldT) {
    int z = blockIdx.z; int b = z >> 3, h = z & 7;
    int s0 = blockIdx.x * 64;
    __shared__ u16 tile[80 * 65];
    for (int idx = threadIdx.x; idx < 64 * 80; idx += 256) {
        int ss = idx / 80, d = idx - ss * 80;
        int s = s0 + ss;
        u16 val = 0;
        if (s < S) val = vsrc[((long)b * S + s) * 640 + h * 80 + d];
        tile[d * 65 + ss] = val;
    }
    __syncthreads();
    for (int idx = threadIdx.x; idx < 80 * 64; idx += 256) {
        int d = idx >> 6, ss = idx & 63;
        int s = s0 + ss;
        if (s < S) Vt[((long)z * 80 + d) * ldT + s] = tile[d * 65 + ss];
    }
}

// ---------------------------------------------------------------------------
// Row softmax in-place on bf16 scores (row length n, stride ld)
// ---------------------------------------------------------------------------
__global__ void softmax_rows(u16* __restrict__ S, int n, int ld) {
    long row = blockIdx.x;
    u16* ptr = S + row * (long)ld;
    __shared__ float red[256];
    int tid = threadIdx.x;
    float v[4];
    float mx = -1e30f;
    int cnt = 0;
    for (int i = tid; i < n; i += 256) { float x = b2f(ptr[i]); v[cnt++] = x; mx = fmaxf(mx, x); }
    red[tid] = mx; __syncthreads();
    for (int s = 128; s > 0; s >>= 1) { if (tid < s) red[tid] = fmaxf(red[tid], red[tid + s]); __syncthreads(); }
    mx = red[0]; __syncthreads();
    float sum = 0.f; cnt = 0;
    for (int i = tid; i < n; i += 256) { float e = __expf(v[cnt] - mx); v[cnt] = e; cnt++; sum += e; }
    red[tid] = sum; __syncthreads();
    for (int s = 128; s > 0; s >>= 1) { if (tid < s) red[tid] += red[tid + s]; __syncthreads(); }
    float inv = 1.0f / red[0];
    cnt = 0;
    for (int i = tid; i < n; i += 256) { ptr[i] = f2b(v[cnt] * inv); cnt++; }
}

// ---------------------------------------------------------------------------
// GEGLU elementwise: p (rows x 5120 bf16) -> h (rows x 2560 bf16)
// ---------------------------------------------------------------------------
__global__ void geglu_k(const u16* __restrict__ pbuf, u16* __restrict__ hbuf, long total) {
    long i = (long)blockIdx.x * 256 + threadIdx.x;
    if (i >= total) return;
    long r = i / 2560, c = i - r * 2560;
    float xh = b2f(pbuf[r * 5120 + c]);
    float gg = b2f(pbuf[r * 5120 + 2560 + c]);
    float u = gg * 0.7978845608f * (1.0f + 0.044715f * gg * gg);
    float th = tanhf(u);
    hbuf[i] = f2b(xh * 0.5f * gg * (1.0f + th));
}

// ---------------------------------------------------------------------------
// f32 -> bf16 convert
// ---------------------------------------------------------------------------
__global__ void f2b_k(const float* __restrict__ src, u16* __restrict__ dst, long n) {
    long i = (long)blockIdx.x * 256 + threadIdx.x;
    if (i < n) dst[i] = f2b(src[i]);
}

// ===========================================================================
extern "C" void kernel_launch(void* const* d_in, const int* in_sizes, int n_in,
                              void* d_out, int out_size, void* d_ws, size_t ws_size,
                              hipStream_t stream) {
    const float* x        = (const float*)d_in[0];
    const float* context  = (const float*)d_in[1];
    const float* gn_gamma = (const float*)d_in[2];
    const float* gn_beta  = (const float*)d_in[3];
    const float* proj_in_w = (const float*)d_in[4];
    const float* proj_in_b = (const float*)d_in[5];
    const float* ln1_g = (const float*)d_in[6];
    const float* ln1_b = (const float*)d_in[7];
    const float* a1_q = (const float*)d_in[8];
    const float* a1_k = (const float*)d_in[9];
    const float* a1_v = (const float*)d_in[10];
    const float* a1_o = (const float*)d_in[11];
    const float* a1_ob = (const float*)d_in[12];
    const float* ln2_g = (const float*)d_in[13];
    const float* ln2_b = (const float*)d_in[14];
    const float* a2_q = (const float*)d_in[15];
    const float* a2_k = (const float*)d_in[16];
    const float* a2_v = (const float*)d_in[17];
    const float* a2_o = (const float*)d_in[18];
    const float* a2_ob = (const float*)d_in[19];
    const float* ln3_g = (const float*)d_in[20];
    const float* ln3_b = (const float*)d_in[21];
    const float* ff1_w = (const float*)d_in[22];
    const float* ff1_b = (const float*)d_in[23];
    const float* ff2_w = (const float*)d_in[24];
    const float* ff2_b = (const float*)d_in[25];
    const float* proj_out_w = (const float*)d_in[26];
    const float* proj_out_b = (const float*)d_in[27];
    float* out = (float*)d_out;

    // ---- workspace carve-up ----
    char* ws = (char*)d_ws;
    size_t off = 0;
    auto alloc = [&](size_t bytes) -> void* {
        void* p = ws + off;
        off += (bytes + 255) & ~(size_t)255;
        return p;
    };
    u16* Wt_pi = (u16*)alloc(640 * 640 * 2);
    u16* Wt_1q = (u16*)alloc(640 * 640 * 2);
    u16* Wt_1k = (u16*)alloc(640 * 640 * 2);
    u16* Wt_1v = (u16*)alloc(640 * 640 * 2);
    u16* Wt_1o = (u16*)alloc(640 * 640 * 2);
    u16* Wt_2q = (u16*)alloc(640 * 640 * 2);
    u16* Wt_2k = (u16*)alloc((size_t)640 * 768 * 2);
    u16* Wt_2v = (u16*)alloc((size_t)640 * 768 * 2);
    u16* Wt_2o = (u16*)alloc(640 * 640 * 2);
    u16* Wt_f1 = (u16*)alloc((size_t)5120 * 640 * 2);
    u16* Wt_f2 = (u16*)alloc((size_t)640 * 2560 * 2);
    u16* Wt_po = (u16*)alloc(640 * 640 * 2);
    float* t   = (float*)alloc((size_t)8192 * 640 * 4);
    u16* bufA  = (u16*)alloc((size_t)8192 * 640 * 2);
    u16* qb    = (u16*)alloc((size_t)8192 * 640 * 2);
    u16* kb    = (u16*)alloc((size_t)8192 * 640 * 2);
    u16* vb    = (u16*)alloc((size_t)8192 * 640 * 2);
    u16* Vt    = (u16*)alloc((size_t)64 * 80 * 1024 * 2);
    u16* ctxb  = (u16*)alloc((size_t)616 * 768 * 2);
    float* stats = (float*)alloc(256 * 2 * 4);
    u16* Sbuf  = (u16*)alloc((size_t)16 * 1024 * 1024 * 2);  // score chunk / ff p-chunk
    u16* hb    = qb;   // alias: GEGLU output chunk (qb dead during FFN)

    const float SCALE = 0.11180339887498949f;  // 80^-0.5

    auto gemm1 = [&](const u16* A, const u16* Bt, const float* bias, const float* res,
                     float* Cf, u16* Cb, int M, int N, int K, int lda, int ldb, int ldc,
                     float alpha) {
        GemmP p{};
        p.A = A; p.B = Bt; p.bias = bias; p.res = res; p.Cf = Cf; p.Cb = Cb;
        p.M = M; p.N = N; p.K = K; p.lda = lda; p.ldb = ldb; p.ldc = ldc;
        p.NH = 1; p.zbA = p.zbB = p.zbC = 0;
        p.sAb = p.sAh = p.sBb = p.sBh = p.sCb = p.sCh = 0;
        p.alpha = alpha;
        dim3 grid((N + 127) / 128, (M + 127) / 128, 1);
        gemm_bt<<<grid, 256, 0, stream>>>(p);
    };

    // ---- 1. weight conversion (f32 KxN -> bf16 NxK) ----
    {
        dim3 blk(32, 8);
        wtrans<<<dim3(20, 20), blk, 0, stream>>>(proj_in_w, Wt_pi, 640, 640);
        wtrans<<<dim3(20, 20), blk, 0, stream>>>(a1_q, Wt_1q, 640, 640);
        wtrans<<<dim3(20, 20), blk, 0, stream>>>(a1_k, Wt_1k, 640, 640);
        wtrans<<<dim3(20, 20), blk, 0, stream>>>(a1_v, Wt_1v, 640, 640);
        wtrans<<<dim3(20, 20), blk, 0, stream>>>(a1_o, Wt_1o, 640, 640);
        wtrans<<<dim3(20, 20), blk, 0, stream>>>(a2_q, Wt_2q, 640, 640);
        wtrans<<<dim3(20, 24), blk, 0, stream>>>(a2_k, Wt_2k, 768, 640);
        wtrans<<<dim3(20, 24), blk, 0, stream>>>(a2_v, Wt_2v, 768, 640);
        wtrans<<<dim3(20, 20), blk, 0, stream>>>(a2_o, Wt_2o, 640, 640);
        wtrans<<<dim3(160, 20), blk, 0, stream>>>(ff1_w, Wt_f1, 640, 5120);
        wtrans<<<dim3(20, 80), blk, 0, stream>>>(ff2_w, Wt_f2, 2560, 640);
        wtrans<<<dim3(20, 20), blk, 0, stream>>>(proj_out_w, Wt_po, 640, 640);
    }

    // ---- 2. GroupNorm -> bufA (bf16), 3. proj_in -> t (f32) ----
    gn_stats<<<256, 256, 0, stream>>>(x, stats);
    gn_apply<<<20480, 256, 0, stream>>>(x, stats, gn_gamma, gn_beta, bufA);
    gemm1(bufA, Wt_pi, proj_in_b, nullptr, t, nullptr, 8192, 640, 640, 640, 640, 640, 1.0f);

    // ---- 4. self-attention ----
    layernorm_rows<<<2048, 256, 0, stream>>>(t, ln1_g, ln1_b, bufA, 8192);
    gemm1(bufA, Wt_1q, nullptr, nullptr, nullptr, qb, 8192, 640, 640, 640, 640, 640, 1.0f);
    gemm1(bufA, Wt_1k, nullptr, nullptr, nullptr, kb, 8192, 640, 640, 640, 640, 640, 1.0f);
    gemm1(bufA, Wt_1v, nullptr, nullptr, nullptr, vb, 8192, 640, 640, 640, 640, 640, 1.0f);
    transpose_v<<<dim3(16, 1, 64), 256, 0, stream>>>(vb, Vt, 1024, 1024);

    for (int c = 0; c < 4; c++) {
        int z0 = c * 16;
        // scores: S = Q @ K^T * scale   (per head, M=N=1024, K=80)
        {
            GemmP p{};
            p.A = qb; p.B = kb; p.bias = nullptr; p.res = nullptr;
            p.Cf = nullptr; p.Cb = Sbuf;
            p.M = 1024; p.N = 1024; p.K = 80;
            p.lda = 640; p.ldb = 640; p.ldc = 1024;
            p.NH = 8; p.zbA = z0; p.zbB = z0; p.zbC = 0;
            p.sAb = (long)1024 * 640; p.sAh = 80;
            p.sBb = (long)1024 * 640; p.sBh = 80;
            p.sCb = (long)8 * 1024 * 1024; p.sCh = (long)1024 * 1024;
            p.alpha = SCALE;
            gemm_bt<<<dim3(8, 8, 16), 256, 0, stream>>>(p);
        }
        softmax_rows<<<16 * 1024, 256, 0, stream>>>(Sbuf, 1024, 1024);
        // PV: O = P @ V  (M=1024, N=80, K=1024), out -> bufA (b,s,h,d)
        {
            GemmP p{};
            p.A = Sbuf; p.B = Vt; p.bias = nullptr; p.res = nullptr;
            p.Cf = nullptr; p.Cb = bufA;
            p.M = 1024; p.N = 80; p.K = 1024;
            p.lda = 1024; p.ldb = 1024; p.ldc = 640;
            p.NH = 8; p.zbA = 0; p.zbB = z0; p.zbC = z0;
            p.sAb = (long)8 * 1024 * 1024; p.sAh = (long)1024 * 1024;
            p.sBb = (long)8 * 80 * 1024; p.sBh = (long)80 * 1024;
            p.sCb = (long)1024 * 640; p.sCh = 80;
            p.alpha = 1.0f;
            gemm_bt<<<dim3(1, 8, 16), 256, 0, stream>>>(p);
        }
    }
    gemm1(bufA, Wt_1o, a1_ob, t, t, nullptr, 8192, 640, 640, 640, 640, 640, 1.0f);

    // ---- 5. cross-attention ----
    layernorm_rows<<<2048, 256, 0, stream>>>(t, ln2_g, ln2_b, bufA, 8192);
    f2b_k<<<1848, 256, 0, stream>>>(context, ctxb, 473088);
    gemm1(bufA, Wt_2q, nullptr, nullptr, nullptr, qb, 8192, 640, 640, 640, 640, 640, 1.0f);
    gemm1(ctxb, Wt_2k, nullptr, nullptr, nullptr, kb, 616, 640, 768, 768, 768, 640, 1.0f);
    gemm1(ctxb, Wt_2v, nullptr, nullptr, nullptr, vb, 616, 640, 768, 768, 768, 640, 1.0f);
    transpose_v<<<dim3(2, 1, 64), 256, 0, stream>>>(vb, Vt, 77, 80);
    {   // scores2: M=1024, N=77, K=80 (ldc padded to 80)
        GemmP p{};
        p.A = qb; p.B = kb; p.bias = nullptr; p.res = nullptr;
        p.Cf = nullptr; p.Cb = Sbuf;
        p.M = 1024; p.N = 77; p.K = 80;
        p.lda = 640; p.ldb = 640; p.ldc = 80;
        p.NH = 8; p.zbA = 0; p.zbB = 0; p.zbC = 0;
        p.sAb = (long)1024 * 640; p.sAh = 80;
        p.sBb = (long)77 * 640; p.sBh = 80;
        p.sCb = (long)8 * 1024 * 80; p.sCh = (long)1024 * 80;
        p.alpha = SCALE;
        gemm_bt<<<dim3(1, 8, 64), 256, 0, stream>>>(p);
    }
    softmax_rows<<<64 * 1024, 256, 0, stream>>>(Sbuf, 77, 80);
    {   // PV2: M=1024, N=80, K=77 -> bufA
        GemmP p{};
        p.A = Sbuf; p.B = Vt; p.bias = nullptr; p.res = nullptr;
        p.Cf = nullptr; p.Cb = bufA;
        p.M = 1024; p.N = 80; p.K = 77;
        p.lda = 80; p.ldb = 80; p.ldc = 640;
        p.NH = 8; p.zbA = 0; p.zbB = 0; p.zbC = 0;
        p.sAb = (long)8 * 1024 * 80; p.sAh = (long)1024 * 80;
        p.sBb = (long)8 * 80 * 80; p.sBh = (long)80 * 80;
        p.sCb = (long)1024 * 640; p.sCh = 80;
        p.alpha = 1.0f;
        gemm_bt<<<dim3(1, 8, 64), 256, 0, stream>>>(p);
    }
    gemm1(bufA, Wt_2o, a2_ob, t, t, nullptr, 8192, 640, 640, 640, 640, 640, 1.0f);

    // ---- 6. FFN (GEGLU), 4 row-chunks of 2048 ----
    layernorm_rows<<<2048, 256, 0, stream>>>(t, ln3_g, ln3_b, bufA, 8192);
    for (int c = 0; c < 4; c++) {
        const u16* Ain = bufA + (long)c * 2048 * 640;
        float* tres = t + (long)c * 2048 * 640;
        gemm1(Ain, Wt_f1, ff1_b, nullptr, nullptr, Sbuf, 2048, 5120, 640, 640, 640, 5120, 1.0f);
        geglu_k<<<20480, 256, 0, stream>>>(Sbuf, hb, (long)2048 * 2560);
        gemm1(hb, Wt_f2, ff2_b, tres, tres, nullptr, 2048, 640, 2560, 2560, 2560, 640, 1.0f);
    }

    // ---- 7. proj_out + x residual -> out ----
    f2b_k<<<20480, 256, 0, stream>>>(t, bufA, 5242880);
    gemm1(bufA, Wt_po, proj_out_b, x, out, nullptr, 8192, 640, 640, 640, 640, 640, 1.0f);
}

// Round 2
// 1256.270 us; speedup vs baseline: 1.3782x; 1.3782x over previous
//
#include <hip/hip_runtime.h>
#include <hip/hip_bf16.h>
#include <math.h>

typedef unsigned short u16;
typedef __attribute__((ext_vector_type(8))) short bf16x8;
typedef __attribute__((ext_vector_type(4))) float f32x4;

__device__ __forceinline__ u16 f2b(float f) {
    union { float f; unsigned u; } v; v.f = f;
    unsigned r = v.u + 0x7fffu + ((v.u >> 16) & 1u);
    return (u16)(r >> 16);
}
__device__ __forceinline__ float b2f(u16 h) {
    union { unsigned u; float f; } v; v.u = ((unsigned)h) << 16; return v.f;
}

// ---------------------------------------------------------------------------
// Generic bf16 MFMA GEMM:  C = alpha * A @ Bt^T (+bias) (+res)
// A: M x K row-major (lda), Bt: N x K row-major (ldb)  [B pre-transposed]
// ---------------------------------------------------------------------------
struct GemmP {
    const u16* A; const u16* B;
    const float* bias; const float* res;
    float* Cf; u16* Cb;
    int M, N, K, lda, ldb, ldc;
    float alpha;
};

__global__ __launch_bounds__(256) void gemm_bt(GemmP p) {
    __shared__ u16 As[128 * 40];
    __shared__ u16 Bs[128 * 40];
    const int tid = threadIdx.x;
    const u16* A = p.A;
    const u16* B = p.B;
    const int m0 = blockIdx.y * 128, n0 = blockIdx.x * 128;
    const int lane = tid & 63, wave = tid >> 6;
    const int quad = lane >> 4, l16 = lane & 15;
    const int wr = (wave >> 1) * 64, wc = (wave & 1) * 64;
    const int sr = tid >> 1, sc = (tid & 1) * 16;

    f32x4 acc[4][4];
#pragma unroll
    for (int i = 0; i < 4; i++)
#pragma unroll
        for (int j = 0; j < 4; j++) acc[i][j] = (f32x4){0.f, 0.f, 0.f, 0.f};

    for (int k0 = 0; k0 < p.K; k0 += 32) {
        {
            int gm = m0 + sr;
            uint4 v0 = {0,0,0,0}, v1 = {0,0,0,0};
            if (gm < p.M) {
                const u16* src = A + (long)gm * p.lda + k0 + sc;
                v0 = *(const uint4*)src;
                v1 = *(const uint4*)(src + 8);
            }
            *(uint4*)&As[sr * 40 + sc] = v0;
            *(uint4*)&As[sr * 40 + sc + 8] = v1;
        }
        {
            int gn = n0 + sr;
            uint4 v0 = {0,0,0,0}, v1 = {0,0,0,0};
            if (gn < p.N) {
                const u16* src = B + (long)gn * p.ldb + k0 + sc;
                v0 = *(const uint4*)src;
                v1 = *(const uint4*)(src + 8);
            }
            *(uint4*)&Bs[sr * 40 + sc] = v0;
            *(uint4*)&Bs[sr * 40 + sc + 8] = v1;
        }
        __syncthreads();

        bf16x8 af[4], bfr[4];
#pragma unroll
        for (int mi = 0; mi < 4; mi++)
            af[mi] = *(const bf16x8*)&As[(wr + mi * 16 + l16) * 40 + quad * 8];
#pragma unroll
        for (int ni = 0; ni < 4; ni++)
            bfr[ni] = *(const bf16x8*)&Bs[(wc + ni * 16 + l16) * 40 + quad * 8];
#pragma unroll
        for (int mi = 0; mi < 4; mi++)
#pragma unroll
            for (int ni = 0; ni < 4; ni++)
                acc[mi][ni] = __builtin_amdgcn_mfma_f32_16x16x32_bf16(af[mi], bfr[ni], acc[mi][ni], 0, 0, 0);
        __syncthreads();
    }

#pragma unroll
    for (int mi = 0; mi < 4; mi++) {
#pragma unroll
        for (int ni = 0; ni < 4; ni++) {
#pragma unroll
            for (int r = 0; r < 4; r++) {
                int row = m0 + wr + mi * 16 + quad * 4 + r;
                int col = n0 + wc + ni * 16 + l16;
                if (row < p.M && col < p.N) {
                    float v = acc[mi][ni][r] * p.alpha;
                    if (p.bias) v += p.bias[col];
                    long idx = (long)row * p.ldc + col;
                    if (p.res) v += p.res[idx];
                    if (p.Cf) p.Cf[idx] = v; else p.Cb[idx] = f2b(v);
                }
            }
        }
    }
}

// ---------------------------------------------------------------------------
// Fused flash attention: one block = (z = b*8+h, 128-row Q tile)
// Q: [b][S][ldq] starting at col h*80 ; K/V likewise ; O -> [b][S][ldo]+h*80
// ---------------------------------------------------------------------------
struct FlashP {
    const u16* Q; const u16* K; const u16* V;
    u16* O;
    int ldq, ldk, ldv, ldo;
    int S, TS, nIter;
    long qBatch, kBatch;
    float scale;
};

__global__ __launch_bounds__(256, 2) void flash_attn(FlashP p) {
    __shared__ u16 shU[128 * 136];   // Q/K staging (stride 104) then P (stride 136)
    __shared__ u16 shV[80 * 136];    // V^T: [d][s], stride 136
    const int z = blockIdx.z, b = z >> 3, h = z & 7;
    const int q0 = blockIdx.x * 128;
    const int tid = threadIdx.x, lane = tid & 63, w = tid >> 6;
    const int quad = lane >> 4, l16 = lane & 15;

    const u16* Qp = p.Q + (long)b * p.qBatch + (long)q0 * p.ldq + h * 80;
    const u16* Kp = p.K + (long)b * p.kBatch + h * 80;
    const u16* Vp = p.V + (long)b * p.kBatch + h * 80;

    // ---- stage Q tile -> shU [row][104], zero-pad d 80..96 ----
    for (int idx = tid; idx < 128 * 12; idx += 256) {
        int row = idx / 12, g = idx - row * 12;
        uint4 v = {0, 0, 0, 0};
        if (g < 10) v = *(const uint4*)(Qp + (long)row * p.ldq + g * 8);
        *(uint4*)&shU[row * 104 + g * 8] = v;
    }
    __syncthreads();
    bf16x8 qf[2][3];
#pragma unroll
    for (int mi = 0; mi < 2; mi++)
#pragma unroll
        for (int kk = 0; kk < 3; kk++)
            qf[mi][kk] = *(const bf16x8*)&shU[(w * 32 + mi * 16 + l16) * 104 + kk * 32 + quad * 8];
    __syncthreads();

    float m_[2][4], l_[2][4];
    f32x4 acc_o[2][5];
#pragma unroll
    for (int mi = 0; mi < 2; mi++) {
#pragma unroll
        for (int r = 0; r < 4; r++) { m_[mi][r] = -1e30f; l_[mi][r] = 0.f; }
#pragma unroll
        for (int ni = 0; ni < 5; ni++) acc_o[mi][ni] = (f32x4){0.f, 0.f, 0.f, 0.f};
    }

    for (int it = 0; it < p.nIter; it++) {
        const int s0 = it * 128;
        // stage K tile -> shU [row][104] (zero pad rows >= TS, d 80..96)
        for (int idx = tid; idx < 128 * 12; idx += 256) {
            int row = idx / 12, g = idx - row * 12;
            uint4 v = {0, 0, 0, 0};
            if (g < 10 && (s0 + row) < p.TS)
                v = *(const uint4*)(Kp + (long)(s0 + row) * p.ldk + g * 8);
            *(uint4*)&shU[row * 104 + g * 8] = v;
        }
        // stage V tile transposed -> shV [d][136]
        for (int idx = tid; idx < 128 * 10; idx += 256) {
            int row = idx / 10, g = idx - row * 10;
            uint4 v = {0, 0, 0, 0};
            if ((s0 + row) < p.TS)
                v = *(const uint4*)(Vp + (long)(s0 + row) * p.ldv + g * 8);
            u16 tmp[8]; *(uint4*)tmp = v;
#pragma unroll
            for (int j = 0; j < 8; j++) shV[(g * 8 + j) * 136 + row] = tmp[j];
        }
        __syncthreads();

        // ---- S = Q @ K^T ----
        f32x4 acc_s[2][8];
#pragma unroll
        for (int mi = 0; mi < 2; mi++)
#pragma unroll
            for (int ni = 0; ni < 8; ni++) acc_s[mi][ni] = (f32x4){0.f, 0.f, 0.f, 0.f};
#pragma unroll
        for (int kk = 0; kk < 3; kk++) {
            bf16x8 kf[8];
#pragma unroll
            for (int ni = 0; ni < 8; ni++)
                kf[ni] = *(const bf16x8*)&shU[(ni * 16 + l16) * 104 + kk * 32 + quad * 8];
#pragma unroll
            for (int mi = 0; mi < 2; mi++)
#pragma unroll
                for (int ni = 0; ni < 8; ni++)
                    acc_s[mi][ni] = __builtin_amdgcn_mfma_f32_16x16x32_bf16(qf[mi][kk], kf[ni], acc_s[mi][ni], 0, 0, 0);
        }
        __syncthreads();  // K consumed; shU becomes P

        // ---- online softmax, write P (bf16) to shU stride 136 ----
#pragma unroll
        for (int mi = 0; mi < 2; mi++) {
#pragma unroll
            for (int ni = 0; ni < 8; ni++) {
                bool valid = (s0 + ni * 16 + l16) < p.TS;
#pragma unroll
                for (int r = 0; r < 4; r++)
                    acc_s[mi][ni][r] = valid ? acc_s[mi][ni][r] * p.scale : -1e30f;
            }
#pragma unroll
            for (int r = 0; r < 4; r++) {
                float rm = acc_s[mi][0][r];
#pragma unroll
                for (int ni = 1; ni < 8; ni++) rm = fmaxf(rm, acc_s[mi][ni][r]);
#pragma unroll
                for (int msk = 1; msk < 16; msk <<= 1) rm = fmaxf(rm, __shfl_xor(rm, msk));
                float mn = fmaxf(m_[mi][r], rm);
                float al = __expf(m_[mi][r] - mn);
                m_[mi][r] = mn;
                float rs = 0.f;
                int prow = (w * 32 + mi * 16 + quad * 4 + r) * 136;
#pragma unroll
                for (int ni = 0; ni < 8; ni++) {
                    float pv = __expf(acc_s[mi][ni][r] - mn);
                    rs += pv;
                    shU[prow + ni * 16 + l16] = f2b(pv);
                }
#pragma unroll
                for (int msk = 1; msk < 16; msk <<= 1) rs += __shfl_xor(rs, msk);
                l_[mi][r] = l_[mi][r] * al + rs;
#pragma unroll
                for (int ni = 0; ni < 5; ni++) acc_o[mi][ni][r] *= al;
            }
        }
        __syncthreads();  // P visible to all waves

        // ---- O += P @ V ----
#pragma unroll
        for (int kk = 0; kk < 4; kk++) {
            bf16x8 vf[5], pf[2];
#pragma unroll
            for (int ni = 0; ni < 5; ni++)
                vf[ni] = *(const bf16x8*)&shV[(ni * 16 + l16) * 136 + kk * 32 + quad * 8];
#pragma unroll
            for (int mi = 0; mi < 2; mi++)
                pf[mi] = *(const bf16x8*)&shU[(w * 32 + mi * 16 + l16) * 136 + kk * 32 + quad * 8];
#pragma unroll
            for (int mi = 0; mi < 2; mi++)
#pragma unroll
                for (int ni = 0; ni < 5; ni++)
                    acc_o[mi][ni] = __builtin_amdgcn_mfma_f32_16x16x32_bf16(pf[mi], vf[ni], acc_o[mi][ni], 0, 0, 0);
        }
        __syncthreads();  // before next-iter staging overwrites shU/shV
    }

    // ---- epilogue ----
    u16* Op = p.O + ((long)b * p.S + q0) * p.ldo + h * 80;
#pragma unroll
    for (int mi = 0; mi < 2; mi++) {
#pragma unroll
        for (int r = 0; r < 4; r++) {
            float inv = 1.0f / l_[mi][r];
            int row = w * 32 + mi * 16 + quad * 4 + r;
#pragma unroll
            for (int ni = 0; ni < 5; ni++)
                Op[(long)row * p.ldo + ni * 16 + l16] = f2b(acc_o[mi][ni][r] * inv);
        }
    }
}

// ---------------------------------------------------------------------------
// Weight transpose + f32->bf16:  W (K x N) -> Wt (N x K)
// ---------------------------------------------------------------------------
__global__ void wtrans(const float* __restrict__ W, u16* __restrict__ Wt, int K, int N) {
    __shared__ float tile[32][33];
    int n0 = blockIdx.x * 32, k0 = blockIdx.y * 32;
    int tx = threadIdx.x, ty = threadIdx.y;
#pragma unroll
    for (int i = 0; i < 4; i++) {
        int k = k0 + ty + i * 8, n = n0 + tx;
        if (k < K && n < N) tile[ty + i * 8][tx] = W[(long)k * N + n];
    }
    __syncthreads();
#pragma unroll
    for (int i = 0; i < 4; i++) {
        int n = n0 + ty + i * 8, k = k0 + tx;
        if (n < N && k < K) Wt[(long)n * K + k] = f2b(tile[tx][ty + i * 8]);
    }
}

// ---------------------------------------------------------------------------
__global__ void gn_stats(const float* __restrict__ x, float* __restrict__ stats) {
    int bid = blockIdx.x;
    int b = bid >> 5, g = bid & 31;
    const float* base = x + (long)b * 32 * 32 * 640 + g * 20;
    float s = 0.f, sq = 0.f;
    for (int idx = threadIdx.x; idx < 32 * 32 * 20; idx += 256) {
        int hw = idx / 20, c = idx - hw * 20;
        float v = base[(long)hw * 640 + c];
        s += v; sq += v * v;
    }
    __shared__ float rs[256], rq[256];
    rs[threadIdx.x] = s; rq[threadIdx.x] = sq; __syncthreads();
    for (int t = 128; t > 0; t >>= 1) {
        if (threadIdx.x < t) { rs[threadIdx.x] += rs[threadIdx.x + t]; rq[threadIdx.x] += rq[threadIdx.x + t]; }
        __syncthreads();
    }
    if (threadIdx.x == 0) {
        float mean = rs[0] / 20480.0f;
        float var = rq[0] / 20480.0f - mean * mean;
        stats[bid * 2] = mean;
        stats[bid * 2 + 1] = rsqrtf(var + 1e-5f);
    }
}

__global__ void gn_apply(const float* __restrict__ x, const float* __restrict__ stats,
                         const float* __restrict__ gamma, const float* __restrict__ beta,
                         u16* __restrict__ out) {
    long i = (long)blockIdx.x * 256 + threadIdx.x;
    int c = (int)(i % 640);
    int b = (int)(i / (32 * 32 * 640));
    int g = c / 20;
    float mean = stats[(b * 32 + g) * 2], inv = stats[(b * 32 + g) * 2 + 1];
    out[i] = f2b((x[i] - mean) * inv * gamma[c] + beta[c]);
}

// ---------------------------------------------------------------------------
__global__ void layernorm_rows(const float* __restrict__ X, const float* __restrict__ g,
                               const float* __restrict__ be, u16* __restrict__ out, int nrows) {
    int row = blockIdx.x * 4 + (threadIdx.x >> 6);
    int lane = threadIdx.x & 63;
    if (row >= nrows) return;
    const float* x = X + (long)row * 640;
    float v[10];
    float s = 0.f;
#pragma unroll
    for (int i = 0; i < 10; i++) { v[i] = x[lane + i * 64]; s += v[i]; }
#pragma unroll
    for (int m = 1; m < 64; m <<= 1) s += __shfl_xor(s, m);
    float mean = s * (1.0f / 640.0f);
    float sq = 0.f;
#pragma unroll
    for (int i = 0; i < 10; i++) { float d = v[i] - mean; sq += d * d; }
#pragma unroll
    for (int m = 1; m < 64; m <<= 1) sq += __shfl_xor(sq, m);
    float inv = rsqrtf(sq * (1.0f / 640.0f) + 1e-5f);
    u16* o = out + (long)row * 640;
#pragma unroll
    for (int i = 0; i < 10; i++) {
        int c = lane + i * 64;
        o[c] = f2b((v[i] - mean) * inv * g[c] + be[c]);
    }
}

// ---------------------------------------------------------------------------
__global__ void geglu_k(const u16* __restrict__ pbuf, u16* __restrict__ hbuf, long total) {
    long i = (long)blockIdx.x * 256 + threadIdx.x;
    if (i >= total) return;
    long r = i / 2560, c = i - r * 2560;
    float xh = b2f(pbuf[r * 5120 + c]);
    float gg = b2f(pbuf[r * 5120 + 2560 + c]);
    float u = gg * 0.7978845608f * (1.0f + 0.044715f * gg * gg);
    float th = tanhf(u);
    hbuf[i] = f2b(xh * 0.5f * gg * (1.0f + th));
}

// ---------------------------------------------------------------------------
__global__ void f2b_k(const float* __restrict__ src, u16* __restrict__ dst, long n) {
    long i = (long)blockIdx.x * 256 + threadIdx.x;
    if (i < n) dst[i] = f2b(src[i]);
}

// ===========================================================================
extern "C" void kernel_launch(void* const* d_in, const int* in_sizes, int n_in,
                              void* d_out, int out_size, void* d_ws, size_t ws_size,
                              hipStream_t stream) {
    const float* x        = (const float*)d_in[0];
    const float* context  = (const float*)d_in[1];
    const float* gn_gamma = (const float*)d_in[2];
    const float* gn_beta  = (const float*)d_in[3];
    const float* proj_in_w = (const float*)d_in[4];
    const float* proj_in_b = (const float*)d_in[5];
    const float* ln1_g = (const float*)d_in[6];
    const float* ln1_b = (const float*)d_in[7];
    const float* a1_q = (const float*)d_in[8];
    const float* a1_k = (const float*)d_in[9];
    const float* a1_v = (const float*)d_in[10];
    const float* a1_o = (const float*)d_in[11];
    const float* a1_ob = (const float*)d_in[12];
    const float* ln2_g = (const float*)d_in[13];
    const float* ln2_b = (const float*)d_in[14];
    const float* a2_q = (const float*)d_in[15];
    const float* a2_k = (const float*)d_in[16];
    const float* a2_v = (const float*)d_in[17];
    const float* a2_o = (const float*)d_in[18];
    const float* a2_ob = (const float*)d_in[19];
    const float* ln3_g = (const float*)d_in[20];
    const float* ln3_b = (const float*)d_in[21];
    const float* ff1_w = (const float*)d_in[22];
    const float* ff1_b = (const float*)d_in[23];
    const float* ff2_w = (const float*)d_in[24];
    const float* ff2_b = (const float*)d_in[25];
    const float* proj_out_w = (const float*)d_in[26];
    const float* proj_out_b = (const float*)d_in[27];
    float* out = (float*)d_out;

    // ---- workspace carve-up ----
    char* ws = (char*)d_ws;
    size_t off = 0;
    auto alloc = [&](size_t bytes) -> void* {
        void* p = ws + off;
        off += (bytes + 255) & ~(size_t)255;
        return p;
    };
    u16* Wt_pi  = (u16*)alloc(640 * 640 * 2);
    u16* Wt_qkv = (u16*)alloc((size_t)1920 * 640 * 2);
    u16* Wt_1o  = (u16*)alloc(640 * 640 * 2);
    u16* Wt_2q  = (u16*)alloc(640 * 640 * 2);
    u16* Wt_kv2 = (u16*)alloc((size_t)1280 * 768 * 2);
    u16* Wt_2o  = (u16*)alloc(640 * 640 * 2);
    u16* Wt_f1  = (u16*)alloc((size_t)5120 * 640 * 2);
    u16* Wt_f2  = (u16*)alloc((size_t)640 * 2560 * 2);
    u16* Wt_po  = (u16*)alloc(640 * 640 * 2);
    float* t    = (float*)alloc((size_t)8192 * 640 * 4);
    u16* bufA   = (u16*)alloc((size_t)8192 * 640 * 2);
    u16* qkvb   = (u16*)alloc((size_t)8192 * 1920 * 2);
    u16* kv2b   = (u16*)alloc((size_t)616 * 1280 * 2);
    u16* ctxb   = (u16*)alloc((size_t)616 * 768 * 2);
    float* stats = (float*)alloc(256 * 2 * 4);
    // FFN chunk buffers alias qkvb (dead during FFN): p (2048x5120) + h (2048x2560)
    u16* pbuf = qkvb;
    u16* hb   = qkvb + (size_t)2048 * 5120;

    const float SCALE = 0.11180339887498949f;  // 80^-0.5

    auto gemm1 = [&](const u16* A, const u16* Bt, const float* bias, const float* res,
                     float* Cf, u16* Cb, int M, int N, int K, int lda, int ldb, int ldc,
                     float alpha) {
        GemmP p{};
        p.A = A; p.B = Bt; p.bias = bias; p.res = res; p.Cf = Cf; p.Cb = Cb;
        p.M = M; p.N = N; p.K = K; p.lda = lda; p.ldb = ldb; p.ldc = ldc;
        p.alpha = alpha;
        dim3 grid((N + 127) / 128, (M + 127) / 128, 1);
        gemm_bt<<<grid, 256, 0, stream>>>(p);
    };

    // ---- 1. weight conversion ----
    {
        dim3 blk(32, 8);
        wtrans<<<dim3(20, 20), blk, 0, stream>>>(proj_in_w, Wt_pi, 640, 640);
        wtrans<<<dim3(20, 20), blk, 0, stream>>>(a1_q, Wt_qkv, 640, 640);
        wtrans<<<dim3(20, 20), blk, 0, stream>>>(a1_k, Wt_qkv + 640 * 640, 640, 640);
        wtrans<<<dim3(20, 20), blk, 0, stream>>>(a1_v, Wt_qkv + 2 * 640 * 640, 640, 640);
        wtrans<<<dim3(20, 20), blk, 0, stream>>>(a1_o, Wt_1o, 640, 640);
        wtrans<<<dim3(20, 20), blk, 0, stream>>>(a2_q, Wt_2q, 640, 640);
        wtrans<<<dim3(20, 24), blk, 0, stream>>>(a2_k, Wt_kv2, 768, 640);
        wtrans<<<dim3(20, 24), blk, 0, stream>>>(a2_v, Wt_kv2 + (size_t)640 * 768, 768, 640);
        wtrans<<<dim3(20, 20), blk, 0, stream>>>(a2_o, Wt_2o, 640, 640);
        wtrans<<<dim3(160, 20), blk, 0, stream>>>(ff1_w, Wt_f1, 640, 5120);
        wtrans<<<dim3(20, 80), blk, 0, stream>>>(ff2_w, Wt_f2, 2560, 640);
        wtrans<<<dim3(20, 20), blk, 0, stream>>>(proj_out_w, Wt_po, 640, 640);
    }

    // ---- 2. GroupNorm + proj_in ----
    gn_stats<<<256, 256, 0, stream>>>(x, stats);
    gn_apply<<<20480, 256, 0, stream>>>(x, stats, gn_gamma, gn_beta, bufA);
    gemm1(bufA, Wt_pi, proj_in_b, nullptr, t, nullptr, 8192, 640, 640, 640, 640, 640, 1.0f);

    // ---- 3. self-attention ----
    layernorm_rows<<<2048, 256, 0, stream>>>(t, ln1_g, ln1_b, bufA, 8192);
    gemm1(bufA, Wt_qkv, nullptr, nullptr, nullptr, qkvb, 8192, 1920, 640, 640, 640, 1920, 1.0f);
    {
        FlashP p{};
        p.Q = qkvb; p.K = qkvb + 640; p.V = qkvb + 1280; p.O = bufA;
        p.ldq = 1920; p.ldk = 1920; p.ldv = 1920; p.ldo = 640;
        p.S = 1024; p.TS = 1024; p.nIter = 8;
        p.qBatch = (long)1024 * 1920; p.kBatch = (long)1024 * 1920;
        p.scale = SCALE;
        flash_attn<<<dim3(8, 1, 64), 256, 0, stream>>>(p);
    }
    gemm1(bufA, Wt_1o, a1_ob, t, t, nullptr, 8192, 640, 640, 640, 640, 640, 1.0f);

    // ---- 4. cross-attention ----
    layernorm_rows<<<2048, 256, 0, stream>>>(t, ln2_g, ln2_b, bufA, 8192);
    f2b_k<<<1848, 256, 0, stream>>>(context, ctxb, 473088);
    gemm1(bufA, Wt_2q, nullptr, nullptr, nullptr, qkvb, 8192, 640, 640, 640, 640, 640, 1.0f);
    gemm1(ctxb, Wt_kv2, nullptr, nullptr, nullptr, kv2b, 616, 1280, 768, 768, 768, 1280, 1.0f);
    {
        FlashP p{};
        p.Q = qkvb; p.K = kv2b; p.V = kv2b + 640; p.O = bufA;
        p.ldq = 640; p.ldk = 1280; p.ldv = 1280; p.ldo = 640;
        p.S = 1024; p.TS = 77; p.nIter = 1;
        p.qBatch = (long)1024 * 640; p.kBatch = (long)77 * 1280;
        p.scale = SCALE;
        flash_attn<<<dim3(8, 1, 64), 256, 0, stream>>>(p);
    }
    gemm1(bufA, Wt_2o, a2_ob, t, t, nullptr, 8192, 640, 640, 640, 640, 640, 1.0f);

    // ---- 5. FFN (GEGLU), 4 row-chunks of 2048 ----
    layernorm_rows<<<2048, 256, 0, stream>>>(t, ln3_g, ln3_b, bufA, 8192);
    for (int c = 0; c < 4; c++) {
        const u16* Ain = bufA + (long)c * 2048 * 640;
        float* tres = t + (long)c * 2048 * 640;
        gemm1(Ain, Wt_f1, ff1_b, nullptr, nullptr, pbuf, 2048, 5120, 640, 640, 640, 5120, 1.0f);
        geglu_k<<<20480, 256, 0, stream>>>(pbuf, hb, (long)2048 * 2560);
        gemm1(hb, Wt_f2, ff2_b, tres, tres, nullptr, 2048, 640, 2560, 2560, 2560, 640, 1.0f);
    }

    // ---- 6. proj_out + x residual ----
    f2b_k<<<20480, 256, 0, stream>>>(t, bufA, 5242880);
    gemm1(bufA, Wt_po, proj_out_b, x, out, nullptr, 8192, 640, 640, 640, 640, 640, 1.0f);
}

// Round 3
// 908.182 us; speedup vs baseline: 1.9065x; 1.3833x over previous
//
#include <hip/hip_runtime.h>
#include <hip/hip_bf16.h>
#include <math.h>

typedef unsigned short u16;
typedef __attribute__((ext_vector_type(8))) short bf16x8;
typedef __attribute__((ext_vector_type(4))) float f32x4;

__device__ __forceinline__ u16 f2b(float f) {
    union { float f; unsigned u; } v; v.f = f;
    unsigned r = v.u + 0x7fffu + ((v.u >> 16) & 1u);
    return (u16)(r >> 16);
}
__device__ __forceinline__ float b2f(u16 h) {
    union { unsigned u; float f; } v; v.u = ((unsigned)h) << 16; return v.f;
}

// ---------------------------------------------------------------------------
// Generic bf16 MFMA GEMM:  C = alpha * A @ Bt^T (+bias) (+res)
// A: M x K row-major (lda) bf16, or f32 via Af. Bt: N x K row-major (ldb).
// ---------------------------------------------------------------------------
struct GemmP {
    const u16* A; const float* Af; const u16* B;
    const float* bias; const float* res;
    float* Cf; u16* Cb;
    int M, N, K, lda, ldb, ldc;
    float alpha;
};

__global__ __launch_bounds__(256) void gemm_bt(GemmP p) {
    __shared__ u16 As[128 * 40];
    __shared__ u16 Bs[128 * 40];
    const int tid = threadIdx.x;
    const int m0 = blockIdx.y * 128, n0 = blockIdx.x * 128;
    const int lane = tid & 63, wave = tid >> 6;
    const int quad = lane >> 4, l16 = lane & 15;
    const int wr = (wave >> 1) * 64, wc = (wave & 1) * 64;
    const int sr = tid >> 1, sc = (tid & 1) * 16;

    f32x4 acc[4][4];
#pragma unroll
    for (int i = 0; i < 4; i++)
#pragma unroll
        for (int j = 0; j < 4; j++) acc[i][j] = (f32x4){0.f, 0.f, 0.f, 0.f};

    for (int k0 = 0; k0 < p.K; k0 += 32) {
        {
            int gm = m0 + sr;
            uint4 v0 = {0,0,0,0}, v1 = {0,0,0,0};
            if (gm < p.M) {
                if (p.Af) {
                    const float* src = p.Af + (long)gm * p.lda + k0 + sc;
                    float4 f0 = *(const float4*)src;
                    float4 f1 = *(const float4*)(src + 4);
                    float4 f2 = *(const float4*)(src + 8);
                    float4 f3 = *(const float4*)(src + 12);
                    u16 tmp[16];
                    tmp[0]=f2b(f0.x); tmp[1]=f2b(f0.y); tmp[2]=f2b(f0.z); tmp[3]=f2b(f0.w);
                    tmp[4]=f2b(f1.x); tmp[5]=f2b(f1.y); tmp[6]=f2b(f1.z); tmp[7]=f2b(f1.w);
                    tmp[8]=f2b(f2.x); tmp[9]=f2b(f2.y); tmp[10]=f2b(f2.z); tmp[11]=f2b(f2.w);
                    tmp[12]=f2b(f3.x); tmp[13]=f2b(f3.y); tmp[14]=f2b(f3.z); tmp[15]=f2b(f3.w);
                    v0 = *(uint4*)tmp; v1 = *(uint4*)(tmp + 8);
                } else {
                    const u16* src = p.A + (long)gm * p.lda + k0 + sc;
                    v0 = *(const uint4*)src;
                    v1 = *(const uint4*)(src + 8);
                }
            }
            *(uint4*)&As[sr * 40 + sc] = v0;
            *(uint4*)&As[sr * 40 + sc + 8] = v1;
        }
        {
            int gn = n0 + sr;
            uint4 v0 = {0,0,0,0}, v1 = {0,0,0,0};
            if (gn < p.N) {
                const u16* src = p.B + (long)gn * p.ldb + k0 + sc;
                v0 = *(const uint4*)src;
                v1 = *(const uint4*)(src + 8);
            }
            *(uint4*)&Bs[sr * 40 + sc] = v0;
            *(uint4*)&Bs[sr * 40 + sc + 8] = v1;
        }
        __syncthreads();

        bf16x8 af[4], bfr[4];
#pragma unroll
        for (int mi = 0; mi < 4; mi++)
            af[mi] = *(const bf16x8*)&As[(wr + mi * 16 + l16) * 40 + quad * 8];
#pragma unroll
        for (int ni = 0; ni < 4; ni++)
            bfr[ni] = *(const bf16x8*)&Bs[(wc + ni * 16 + l16) * 40 + quad * 8];
#pragma unroll
        for (int mi = 0; mi < 4; mi++)
#pragma unroll
            for (int ni = 0; ni < 4; ni++)
                acc[mi][ni] = __builtin_amdgcn_mfma_f32_16x16x32_bf16(af[mi], bfr[ni], acc[mi][ni], 0, 0, 0);
        __syncthreads();
    }

#pragma unroll
    for (int mi = 0; mi < 4; mi++) {
#pragma unroll
        for (int ni = 0; ni < 4; ni++) {
#pragma unroll
            for (int r = 0; r < 4; r++) {
                int row = m0 + wr + mi * 16 + quad * 4 + r;
                int col = n0 + wc + ni * 16 + l16;
                if (row < p.M && col < p.N) {
                    float v = acc[mi][ni][r] * p.alpha;
                    if (p.bias) v += p.bias[col];
                    long idx = (long)row * p.ldc + col;
                    if (p.res) v += p.res[idx];
                    if (p.Cf) p.Cf[idx] = v; else p.Cb[idx] = f2b(v);
                }
            }
        }
    }
}

// ---------------------------------------------------------------------------
// Fused ff1 + GEGLU: H = geglu(A @ W1 + b1), per-block dual 128x128 tiles.
// A: M x K bf16 (lda). Bx/Bg: 2560 x K bf16 (ldb). H: M x 2560 bf16.
// M, K multiples of 128/32; grid = (2560/128, M/128).
// ---------------------------------------------------------------------------
struct GegluP {
    const u16* A; const u16* Bx; const u16* Bg;
    const float* bx; const float* bg;
    u16* H;
    int K, lda, ldb, ldh;
};

__global__ __launch_bounds__(256) void gemm_geglu(GegluP p) {
    __shared__ u16 As[128 * 40];
    __shared__ u16 Bxs[128 * 40];
    __shared__ u16 Bgs[128 * 40];
    const int tid = threadIdx.x;
    const int m0 = blockIdx.y * 128, n0 = blockIdx.x * 128;
    const int lane = tid & 63, wave = tid >> 6;
    const int quad = lane >> 4, l16 = lane & 15;
    const int wr = (wave >> 1) * 64, wc = (wave & 1) * 64;
    const int sr = tid >> 1, sc = (tid & 1) * 16;

    f32x4 ax[4][4], ag[4][4];
#pragma unroll
    for (int i = 0; i < 4; i++)
#pragma unroll
        for (int j = 0; j < 4; j++) { ax[i][j] = (f32x4){0.f,0.f,0.f,0.f}; ag[i][j] = (f32x4){0.f,0.f,0.f,0.f}; }

    for (int k0 = 0; k0 < p.K; k0 += 32) {
        {
            const u16* src = p.A + (long)(m0 + sr) * p.lda + k0 + sc;
            *(uint4*)&As[sr * 40 + sc] = *(const uint4*)src;
            *(uint4*)&As[sr * 40 + sc + 8] = *(const uint4*)(src + 8);
        }
        {
            const u16* src = p.Bx + (long)(n0 + sr) * p.ldb + k0 + sc;
            *(uint4*)&Bxs[sr * 40 + sc] = *(const uint4*)src;
            *(uint4*)&Bxs[sr * 40 + sc + 8] = *(const uint4*)(src + 8);
        }
        {
            const u16* src = p.Bg + (long)(n0 + sr) * p.ldb + k0 + sc;
            *(uint4*)&Bgs[sr * 40 + sc] = *(const uint4*)src;
            *(uint4*)&Bgs[sr * 40 + sc + 8] = *(const uint4*)(src + 8);
        }
        __syncthreads();

        bf16x8 af[4], bxf[4], bgf[4];
#pragma unroll
        for (int mi = 0; mi < 4; mi++)
            af[mi] = *(const bf16x8*)&As[(wr + mi * 16 + l16) * 40 + quad * 8];
#pragma unroll
        for (int ni = 0; ni < 4; ni++)
            bxf[ni] = *(const bf16x8*)&Bxs[(wc + ni * 16 + l16) * 40 + quad * 8];
#pragma unroll
        for (int mi = 0; mi < 4; mi++)
#pragma unroll
            for (int ni = 0; ni < 4; ni++)
                ax[mi][ni] = __builtin_amdgcn_mfma_f32_16x16x32_bf16(af[mi], bxf[ni], ax[mi][ni], 0, 0, 0);
#pragma unroll
        for (int ni = 0; ni < 4; ni++)
            bgf[ni] = *(const bf16x8*)&Bgs[(wc + ni * 16 + l16) * 40 + quad * 8];
#pragma unroll
        for (int mi = 0; mi < 4; mi++)
#pragma unroll
            for (int ni = 0; ni < 4; ni++)
                ag[mi][ni] = __builtin_amdgcn_mfma_f32_16x16x32_bf16(af[mi], bgf[ni], ag[mi][ni], 0, 0, 0);
        __syncthreads();
    }

    // epilogue: h = xh * g * sigmoid(2u), u = 0.79788456*g*(1+0.044715 g^2)
#pragma unroll
    for (int mi = 0; mi < 4; mi++) {
#pragma unroll
        for (int ni = 0; ni < 4; ni++) {
#pragma unroll
            for (int r = 0; r < 4; r++) {
                int row = m0 + wr + mi * 16 + quad * 4 + r;
                int col = wc + ni * 16 + l16;   // 0..127 within tile
                float xh = ax[mi][ni][r] + p.bx[n0 + col];
                float g  = ag[mi][ni][r] + p.bg[n0 + col];
                float u  = 0.7978845608f * g * (1.0f + 0.044715f * g * g);
                float s  = 1.0f / (1.0f + __expf(-2.0f * u));
                p.H[(long)row * p.ldh + n0 + col] = f2b(xh * g * s);
            }
        }
    }
}

// ---------------------------------------------------------------------------
// Fused flash attention: one block = (z = b*8+h, 128-row Q tile)
// ---------------------------------------------------------------------------
struct FlashP {
    const u16* Q; const u16* K; const u16* V;
    u16* O;
    int ldq, ldk, ldv, ldo;
    int S, TS, nIter;
    long qBatch, kBatch;
    float scale;
};

__global__ __launch_bounds__(256, 2) void flash_attn(FlashP p) {
    __shared__ u16 shU[128 * 136];
    __shared__ u16 shV[80 * 136];
    const int z = blockIdx.z, b = z >> 3, h = z & 7;
    const int q0 = blockIdx.x * 128;
    const int tid = threadIdx.x, lane = tid & 63, w = tid >> 6;
    const int quad = lane >> 4, l16 = lane & 15;

    const u16* Qp = p.Q + (long)b * p.qBatch + (long)q0 * p.ldq + h * 80;
    const u16* Kp = p.K + (long)b * p.kBatch + h * 80;
    const u16* Vp = p.V + (long)b * p.kBatch + h * 80;

    for (int idx = tid; idx < 128 * 12; idx += 256) {
        int row = idx / 12, g = idx - row * 12;
        uint4 v = {0, 0, 0, 0};
        if (g < 10) v = *(const uint4*)(Qp + (long)row * p.ldq + g * 8);
        *(uint4*)&shU[row * 104 + g * 8] = v;
    }
    __syncthreads();
    bf16x8 qf[2][3];
#pragma unroll
    for (int mi = 0; mi < 2; mi++)
#pragma unroll
        for (int kk = 0; kk < 3; kk++)
            qf[mi][kk] = *(const bf16x8*)&shU[(w * 32 + mi * 16 + l16) * 104 + kk * 32 + quad * 8];
    __syncthreads();

    float m_[2][4], l_[2][4];
    f32x4 acc_o[2][5];
#pragma unroll
    for (int mi = 0; mi < 2; mi++) {
#pragma unroll
        for (int r = 0; r < 4; r++) { m_[mi][r] = -1e30f; l_[mi][r] = 0.f; }
#pragma unroll
        for (int ni = 0; ni < 5; ni++) acc_o[mi][ni] = (f32x4){0.f, 0.f, 0.f, 0.f};
    }

    for (int it = 0; it < p.nIter; it++) {
        const int s0 = it * 128;
        for (int idx = tid; idx < 128 * 12; idx += 256) {
            int row = idx / 12, g = idx - row * 12;
            uint4 v = {0, 0, 0, 0};
            if (g < 10 && (s0 + row) < p.TS)
                v = *(const uint4*)(Kp + (long)(s0 + row) * p.ldk + g * 8);
            *(uint4*)&shU[row * 104 + g * 8] = v;
        }
        for (int idx = tid; idx < 128 * 10; idx += 256) {
            int row = idx / 10, g = idx - row * 10;
            uint4 v = {0, 0, 0, 0};
            if ((s0 + row) < p.TS)
                v = *(const uint4*)(Vp + (long)(s0 + row) * p.ldv + g * 8);
            u16 tmp[8]; *(uint4*)tmp = v;
#pragma unroll
            for (int j = 0; j < 8; j++) shV[(g * 8 + j) * 136 + row] = tmp[j];
        }
        __syncthreads();

        f32x4 acc_s[2][8];
#pragma unroll
        for (int mi = 0; mi < 2; mi++)
#pragma unroll
            for (int ni = 0; ni < 8; ni++) acc_s[mi][ni] = (f32x4){0.f, 0.f, 0.f, 0.f};
#pragma unroll
        for (int kk = 0; kk < 3; kk++) {
            bf16x8 kf[8];
#pragma unroll
            for (int ni = 0; ni < 8; ni++)
                kf[ni] = *(const bf16x8*)&shU[(ni * 16 + l16) * 104 + kk * 32 + quad * 8];
#pragma unroll
            for (int mi = 0; mi < 2; mi++)
#pragma unroll
                for (int ni = 0; ni < 8; ni++)
                    acc_s[mi][ni] = __builtin_amdgcn_mfma_f32_16x16x32_bf16(qf[mi][kk], kf[ni], acc_s[mi][ni], 0, 0, 0);
        }
        __syncthreads();

#pragma unroll
        for (int mi = 0; mi < 2; mi++) {
#pragma unroll
            for (int ni = 0; ni < 8; ni++) {
                bool valid = (s0 + ni * 16 + l16) < p.TS;
#pragma unroll
                for (int r = 0; r < 4; r++)
                    acc_s[mi][ni][r] = valid ? acc_s[mi][ni][r] * p.scale : -1e30f;
            }
#pragma unroll
            for (int r = 0; r < 4; r++) {
                float rm = acc_s[mi][0][r];
#pragma unroll
                for (int ni = 1; ni < 8; ni++) rm = fmaxf(rm, acc_s[mi][ni][r]);
#pragma unroll
                for (int msk = 1; msk < 16; msk <<= 1) rm = fmaxf(rm, __shfl_xor(rm, msk));
                float mn = fmaxf(m_[mi][r], rm);
                float al = __expf(m_[mi][r] - mn);
                m_[mi][r] = mn;
                float rs = 0.f;
                int prow = (w * 32 + mi * 16 + quad * 4 + r) * 136;
#pragma unroll
                for (int ni = 0; ni < 8; ni++) {
                    float pv = __expf(acc_s[mi][ni][r] - mn);
                    rs += pv;
                    shU[prow + ni * 16 + l16] = f2b(pv);
                }
#pragma unroll
                for (int msk = 1; msk < 16; msk <<= 1) rs += __shfl_xor(rs, msk);
                l_[mi][r] = l_[mi][r] * al + rs;
#pragma unroll
                for (int ni = 0; ni < 5; ni++) acc_o[mi][ni][r] *= al;
            }
        }
        __syncthreads();

#pragma unroll
        for (int kk = 0; kk < 4; kk++) {
            bf16x8 vf[5], pf[2];
#pragma unroll
            for (int ni = 0; ni < 5; ni++)
                vf[ni] = *(const bf16x8*)&shV[(ni * 16 + l16) * 136 + kk * 32 + quad * 8];
#pragma unroll
            for (int mi = 0; mi < 2; mi++)
                pf[mi] = *(const bf16x8*)&shU[(w * 32 + mi * 16 + l16) * 136 + kk * 32 + quad * 8];
#pragma unroll
            for (int mi = 0; mi < 2; mi++)
#pragma unroll
                for (int ni = 0; ni < 5; ni++)
                    acc_o[mi][ni] = __builtin_amdgcn_mfma_f32_16x16x32_bf16(pf[mi], vf[ni], acc_o[mi][ni], 0, 0, 0);
        }
        __syncthreads();
    }

    u16* Op = p.O + ((long)b * p.S + q0) * p.ldo + h * 80;
#pragma unroll
    for (int mi = 0; mi < 2; mi++) {
#pragma unroll
        for (int r = 0; r < 4; r++) {
            float inv = 1.0f / l_[mi][r];
            int row = w * 32 + mi * 16 + quad * 4 + r;
#pragma unroll
            for (int ni = 0; ni < 5; ni++)
                Op[(long)row * p.ldo + ni * 16 + l16] = f2b(acc_o[mi][ni][r] * inv);
        }
    }
}

// ---------------------------------------------------------------------------
// Batched weight transpose + f32->bf16:  W (K x N) -> Wt (N x K), grid.z picks pair
// ---------------------------------------------------------------------------
struct WT8 { const float* W[8]; u16* Wt[8]; };

__global__ void wtrans8(WT8 p, int K, int N) {
    __shared__ float tile[32][33];
    const float* W = p.W[blockIdx.z];
    u16* Wt = p.Wt[blockIdx.z];
    int n0 = blockIdx.x * 32, k0 = blockIdx.y * 32;
    int tx = threadIdx.x, ty = threadIdx.y;
#pragma unroll
    for (int i = 0; i < 4; i++) {
        int k = k0 + ty + i * 8, n = n0 + tx;
        if (k < K && n < N) tile[ty + i * 8][tx] = W[(long)k * N + n];
    }
    __syncthreads();
#pragma unroll
    for (int i = 0; i < 4; i++) {
        int n = n0 + ty + i * 8, k = k0 + tx;
        if (n < N && k < K) Wt[(long)n * K + k] = f2b(tile[tx][ty + i * 8]);
    }
}

// ---------------------------------------------------------------------------
__global__ void gn_stats(const float* __restrict__ x, float* __restrict__ stats) {
    int bid = blockIdx.x;
    int b = bid >> 5, g = bid & 31;
    const float* base = x + (long)b * 32 * 32 * 640 + g * 20;
    float s = 0.f, sq = 0.f;
    for (int idx = threadIdx.x; idx < 32 * 32 * 20; idx += 256) {
        int hw = idx / 20, c = idx - hw * 20;
        float v = base[(long)hw * 640 + c];
        s += v; sq += v * v;
    }
    __shared__ float rs[256], rq[256];
    rs[threadIdx.x] = s; rq[threadIdx.x] = sq; __syncthreads();
    for (int t = 128; t > 0; t >>= 1) {
        if (threadIdx.x < t) { rs[threadIdx.x] += rs[threadIdx.x + t]; rq[threadIdx.x] += rq[threadIdx.x + t]; }
        __syncthreads();
    }
    if (threadIdx.x == 0) {
        float mean = rs[0] / 20480.0f;
        float var = rq[0] / 20480.0f - mean * mean;
        stats[bid * 2] = mean;
        stats[bid * 2 + 1] = rsqrtf(var + 1e-5f);
    }
}

__global__ void gn_apply(const float* __restrict__ x, const float* __restrict__ stats,
                         const float* __restrict__ gamma, const float* __restrict__ beta,
                         u16* __restrict__ out) {
    long i = (long)blockIdx.x * 256 + threadIdx.x;
    int c = (int)(i % 640);
    int b = (int)(i / (32 * 32 * 640));
    int g = c / 20;
    float mean = stats[(b * 32 + g) * 2], inv = stats[(b * 32 + g) * 2 + 1];
    out[i] = f2b((x[i] - mean) * inv * gamma[c] + beta[c]);
}

// ---------------------------------------------------------------------------
__global__ void layernorm_rows(const float* __restrict__ X, const float* __restrict__ g,
                               const float* __restrict__ be, u16* __restrict__ out, int nrows) {
    int row = blockIdx.x * 4 + (threadIdx.x >> 6);
    int lane = threadIdx.x & 63;
    if (row >= nrows) return;
    const float* x = X + (long)row * 640;
    float v[10];
    float s = 0.f;
#pragma unroll
    for (int i = 0; i < 10; i++) { v[i] = x[lane + i * 64]; s += v[i]; }
#pragma unroll
    for (int m = 1; m < 64; m <<= 1) s += __shfl_xor(s, m);
    float mean = s * (1.0f / 640.0f);
    float sq = 0.f;
#pragma unroll
    for (int i = 0; i < 10; i++) { float d = v[i] - mean; sq += d * d; }
#pragma unroll
    for (int m = 1; m < 64; m <<= 1) sq += __shfl_xor(sq, m);
    float inv = rsqrtf(sq * (1.0f / 640.0f) + 1e-5f);
    u16* o = out + (long)row * 640;
#pragma unroll
    for (int i = 0; i < 10; i++) {
        int c = lane + i * 64;
        o[c] = f2b((v[i] - mean) * inv * g[c] + be[c]);
    }
}

// ---------------------------------------------------------------------------
__global__ void f2b_k(const float* __restrict__ src, u16* __restrict__ dst, long n) {
    long i = (long)blockIdx.x * 256 + threadIdx.x;
    if (i < n) dst[i] = f2b(src[i]);
}

// ===========================================================================
extern "C" void kernel_launch(void* const* d_in, const int* in_sizes, int n_in,
                              void* d_out, int out_size, void* d_ws, size_t ws_size,
                              hipStream_t stream) {
    const float* x        = (const float*)d_in[0];
    const float* context  = (const float*)d_in[1];
    const float* gn_gamma = (const float*)d_in[2];
    const float* gn_beta  = (const float*)d_in[3];
    const float* proj_in_w = (const float*)d_in[4];
    const float* proj_in_b = (const float*)d_in[5];
    const float* ln1_g = (const float*)d_in[6];
    const float* ln1_b = (const float*)d_in[7];
    const float* a1_q = (const float*)d_in[8];
    const float* a1_k = (const float*)d_in[9];
    const float* a1_v = (const float*)d_in[10];
    const float* a1_o = (const float*)d_in[11];
    const float* a1_ob = (const float*)d_in[12];
    const float* ln2_g = (const float*)d_in[13];
    const float* ln2_b = (const float*)d_in[14];
    const float* a2_q = (const float*)d_in[15];
    const float* a2_k = (const float*)d_in[16];
    const float* a2_v = (const float*)d_in[17];
    const float* a2_o = (const float*)d_in[18];
    const float* a2_ob = (const float*)d_in[19];
    const float* ln3_g = (const float*)d_in[20];
    const float* ln3_b = (const float*)d_in[21];
    const float* ff1_w = (const float*)d_in[22];
    const float* ff1_b = (const float*)d_in[23];
    const float* ff2_w = (const float*)d_in[24];
    const float* ff2_b = (const float*)d_in[25];
    const float* proj_out_w = (const float*)d_in[26];
    const float* proj_out_b = (const float*)d_in[27];
    float* out = (float*)d_out;

    // ---- workspace carve-up ----
    char* ws = (char*)d_ws;
    size_t off = 0;
    auto alloc = [&](size_t bytes) -> void* {
        void* p = ws + off;
        off += (bytes + 255) & ~(size_t)255;
        return p;
    };
    u16* Wt_pi  = (u16*)alloc(640 * 640 * 2);
    u16* Wt_qkv = (u16*)alloc((size_t)1920 * 640 * 2);
    u16* Wt_1o  = (u16*)alloc(640 * 640 * 2);
    u16* Wt_2q  = (u16*)alloc(640 * 640 * 2);
    u16* Wt_kv2 = (u16*)alloc((size_t)1280 * 768 * 2);
    u16* Wt_2o  = (u16*)alloc(640 * 640 * 2);
    u16* Wt_f1  = (u16*)alloc((size_t)5120 * 640 * 2);
    u16* Wt_f2  = (u16*)alloc((size_t)640 * 2560 * 2);
    u16* Wt_po  = (u16*)alloc(640 * 640 * 2);
    float* t    = (float*)alloc((size_t)8192 * 640 * 4);
    u16* bufA   = (u16*)alloc((size_t)8192 * 640 * 2);
    u16* big    = (u16*)alloc((size_t)8192 * 2560 * 2);  // qkv (8192x1920) / h (8192x2560)
    u16* kv2b   = (u16*)alloc((size_t)616 * 1280 * 2);
    u16* ctxb   = (u16*)alloc((size_t)616 * 768 * 2);
    float* stats = (float*)alloc(256 * 2 * 4);
    u16* qkvb = big;
    u16* hb   = big;

    const float SCALE = 0.11180339887498949f;

    auto gemm1 = [&](const u16* A, const float* Af, const u16* Bt, const float* bias,
                     const float* res, float* Cf, u16* Cb, int M, int N, int K,
                     int lda, int ldb, int ldc, float alpha) {
        GemmP p{};
        p.A = A; p.Af = Af; p.B = Bt; p.bias = bias; p.res = res; p.Cf = Cf; p.Cb = Cb;
        p.M = M; p.N = N; p.K = K; p.lda = lda; p.ldb = ldb; p.ldc = ldc;
        p.alpha = alpha;
        dim3 grid((N + 127) / 128, (M + 127) / 128, 1);
        gemm_bt<<<grid, 256, 0, stream>>>(p);
    };

    // ---- 1. weight conversion (4 batched dispatches) ----
    {
        dim3 blk(32, 8);
        WT8 sq{};
        sq.W[0] = proj_in_w; sq.Wt[0] = Wt_pi;
        sq.W[1] = a1_q;      sq.Wt[1] = Wt_qkv;
        sq.W[2] = a1_k;      sq.Wt[2] = Wt_qkv + 640 * 640;
        sq.W[3] = a1_v;      sq.Wt[3] = Wt_qkv + 2 * 640 * 640;
        sq.W[4] = a1_o;      sq.Wt[4] = Wt_1o;
        sq.W[5] = a2_q;      sq.Wt[5] = Wt_2q;
        sq.W[6] = a2_o;      sq.Wt[6] = Wt_2o;
        sq.W[7] = proj_out_w; sq.Wt[7] = Wt_po;
        wtrans8<<<dim3(20, 20, 8), blk, 0, stream>>>(sq, 640, 640);
        WT8 kv{};
        kv.W[0] = a2_k; kv.Wt[0] = Wt_kv2;
        kv.W[1] = a2_v; kv.Wt[1] = Wt_kv2 + (size_t)640 * 768;
        wtrans8<<<dim3(20, 24, 2), blk, 0, stream>>>(kv, 768, 640);
        WT8 f1{}; f1.W[0] = ff1_w; f1.Wt[0] = Wt_f1;
        wtrans8<<<dim3(160, 20, 1), blk, 0, stream>>>(f1, 640, 5120);
        WT8 f2{}; f2.W[0] = ff2_w; f2.Wt[0] = Wt_f2;
        wtrans8<<<dim3(20, 80, 1), blk, 0, stream>>>(f2, 2560, 640);
    }

    // ---- 2. GroupNorm + proj_in ----
    gn_stats<<<256, 256, 0, stream>>>(x, stats);
    gn_apply<<<20480, 256, 0, stream>>>(x, stats, gn_gamma, gn_beta, bufA);
    gemm1(bufA, nullptr, Wt_pi, proj_in_b, nullptr, t, nullptr, 8192, 640, 640, 640, 640, 640, 1.0f);

    // ---- 3. self-attention ----
    layernorm_rows<<<2048, 256, 0, stream>>>(t, ln1_g, ln1_b, bufA, 8192);
    gemm1(bufA, nullptr, Wt_qkv, nullptr, nullptr, nullptr, qkvb, 8192, 1920, 640, 640, 640, 1920, 1.0f);
    {
        FlashP p{};
        p.Q = qkvb; p.K = qkvb + 640; p.V = qkvb + 1280; p.O = bufA;
        p.ldq = 1920; p.ldk = 1920; p.ldv = 1920; p.ldo = 640;
        p.S = 1024; p.TS = 1024; p.nIter = 8;
        p.qBatch = (long)1024 * 1920; p.kBatch = (long)1024 * 1920;
        p.scale = SCALE;
        flash_attn<<<dim3(8, 1, 64), 256, 0, stream>>>(p);
    }
    gemm1(bufA, nullptr, Wt_1o, a1_ob, t, t, nullptr, 8192, 640, 640, 640, 640, 640, 1.0f);

    // ---- 4. cross-attention ----
    layernorm_rows<<<2048, 256, 0, stream>>>(t, ln2_g, ln2_b, bufA, 8192);
    f2b_k<<<1848, 256, 0, stream>>>(context, ctxb, 473088);
    gemm1(bufA, nullptr, Wt_2q, nullptr, nullptr, nullptr, qkvb, 8192, 640, 640, 640, 640, 640, 1.0f);
    gemm1(ctxb, nullptr, Wt_kv2, nullptr, nullptr, nullptr, kv2b, 616, 1280, 768, 768, 768, 1280, 1.0f);
    {
        FlashP p{};
        p.Q = qkvb; p.K = kv2b; p.V = kv2b + 640; p.O = bufA;
        p.ldq = 640; p.ldk = 1280; p.ldv = 1280; p.ldo = 640;
        p.S = 1024; p.TS = 77; p.nIter = 1;
        p.qBatch = (long)1024 * 640; p.kBatch = (long)77 * 1280;
        p.scale = SCALE;
        flash_attn<<<dim3(8, 1, 64), 256, 0, stream>>>(p);
    }
    gemm1(bufA, nullptr, Wt_2o, a2_ob, t, t, nullptr, 8192, 640, 640, 640, 640, 640, 1.0f);

    // ---- 5. FFN: fused ff1+GEGLU, then ff2 ----
    layernorm_rows<<<2048, 256, 0, stream>>>(t, ln3_g, ln3_b, bufA, 8192);
    {
        GegluP p{};
        p.A = bufA; p.Bx = Wt_f1; p.Bg = Wt_f1 + (size_t)2560 * 640;
        p.bx = ff1_b; p.bg = ff1_b + 2560;
        p.H = hb;
        p.K = 640; p.lda = 640; p.ldb = 640; p.ldh = 2560;
        gemm_geglu<<<dim3(20, 64), 256, 0, stream>>>(p);
    }
    gemm1(hb, nullptr, Wt_f2, ff2_b, t, t, nullptr, 8192, 640, 2560, 2560, 2560, 640, 1.0f);

    // ---- 6. proj_out + x residual (reads f32 t directly) ----
    gemm1(nullptr, t, Wt_po, proj_out_b, x, out, nullptr, 8192, 640, 640, 640, 640, 640, 1.0f);
}

// Round 4
// 852.024 us; speedup vs baseline: 2.0321x; 1.0659x over previous
//
#include <hip/hip_runtime.h>
#include <hip/hip_bf16.h>
#include <math.h>

typedef unsigned short u16;
typedef unsigned int u32;
typedef __attribute__((ext_vector_type(8))) short bf16x8;
typedef __attribute__((ext_vector_type(4))) float f32x4;

__device__ __forceinline__ u16 f2b(float f) {
    union { float f; unsigned u; } v; v.f = f;
    unsigned r = v.u + 0x7fffu + ((v.u >> 16) & 1u);
    return (u16)(r >> 16);
}
__device__ __forceinline__ float b2f(u16 h) {
    union { unsigned u; float f; } v; v.u = ((unsigned)h) << 16; return v.f;
}

// global -> LDS direct DMA, 16 bytes per lane. LDS dest = uniform base + lane*16.
__device__ __forceinline__ void gld16(const u16* gp, u16* lp) {
    auto g = (const __attribute__((address_space(1))) u32*)gp;
    auto l = (__attribute__((address_space(3))) u32*)lp;
    __builtin_amdgcn_global_load_lds(g, l, 16, 0, 0);
}

// LDS 16B-block swizzle: row stride 32 u16 = four 16B blocks; physical block
// for logical K-block q at row r is (q + (r>>1)) & 3  -> 2-way-free ds_read_b128.
__device__ __forceinline__ int swz(int row, int q) { return (q + (row >> 1)) & 3; }

// ---------------------------------------------------------------------------
// Generic bf16 MFMA GEMM:  C = alpha * A @ Bt^T (+bias) (+res)
// A: M x K row-major (lda) bf16, or f32 via Af. Bt: N x K row-major (ldb).
// K % 32 == 0. lda/ldb % 8 == 0. OOB M/N rows may read garbage inside ws
// (guarded at store); keep a guard region after the last A/B buffer.
// ---------------------------------------------------------------------------
struct GemmP {
    const u16* A; const float* Af; const u16* B;
    const float* bias; const float* res;
    float* Cf; u16* Cb;
    int M, N, K, lda, ldb, ldc;
    float alpha;
};

__global__ __launch_bounds__(256) void gemm_bt(GemmP p) {
    __shared__ u16 As[128 * 32];
    __shared__ u16 Bs[128 * 32];
    const int tid = threadIdx.x;
    const int m0 = blockIdx.y * 128, n0 = blockIdx.x * 128;
    const int lane = tid & 63, wave = tid >> 6;
    const int quad = lane >> 4, l16 = lane & 15;
    const int wr = (wave >> 1) * 64, wc = (wave & 1) * 64;
    const int srow = lane >> 2, pcb = lane & 3;

    f32x4 acc[4][4];
#pragma unroll
    for (int i = 0; i < 4; i++)
#pragma unroll
        for (int j = 0; j < 4; j++) acc[i][j] = (f32x4){0.f, 0.f, 0.f, 0.f};

    for (int k0 = 0; k0 < p.K; k0 += 32) {
        if (p.Af) {
            // A from f32 with on-the-fly convert (register staging, swizzled store)
            int row = tid >> 1, half = tid & 1;
            const float* src = p.Af + (long)(m0 + row) * p.lda + k0 + half * 16;
            u16 tmp[16];
#pragma unroll
            for (int i2 = 0; i2 < 4; i2++) {
                float4 f = *(const float4*)(src + i2 * 4);
                tmp[i2 * 4 + 0] = f2b(f.x); tmp[i2 * 4 + 1] = f2b(f.y);
                tmp[i2 * 4 + 2] = f2b(f.z); tmp[i2 * 4 + 3] = f2b(f.w);
            }
            *(uint4*)&As[row * 32 + swz(row, 2 * half) * 8]     = *(uint4*)tmp;
            *(uint4*)&As[row * 32 + swz(row, 2 * half + 1) * 8] = *(uint4*)(tmp + 8);
#pragma unroll
            for (int j = 0; j < 2; j++) {
                int rbase = wave * 32 + j * 16;
                int r = rbase + srow;
                int lcb = (pcb - (r >> 1)) & 3;
                gld16(p.B + (long)(n0 + r) * p.ldb + k0 + lcb * 8, &Bs[rbase * 32]);
            }
        } else {
#pragma unroll
            for (int j = 0; j < 2; j++) {
                int rbase = wave * 32 + j * 16;
                int r = rbase + srow;
                int lcb = (pcb - (r >> 1)) & 3;
                gld16(p.A + (long)(m0 + r) * p.lda + k0 + lcb * 8, &As[rbase * 32]);
                gld16(p.B + (long)(n0 + r) * p.ldb + k0 + lcb * 8, &Bs[rbase * 32]);
            }
        }
        __syncthreads();

        bf16x8 af[4], bfr[4];
#pragma unroll
        for (int mi = 0; mi < 4; mi++) {
            int row = wr + mi * 16 + l16;
            af[mi] = *(const bf16x8*)&As[row * 32 + swz(row, quad) * 8];
        }
#pragma unroll
        for (int ni = 0; ni < 4; ni++) {
            int row = wc + ni * 16 + l16;
            bfr[ni] = *(const bf16x8*)&Bs[row * 32 + swz(row, quad) * 8];
        }
#pragma unroll
        for (int mi = 0; mi < 4; mi++)
#pragma unroll
            for (int ni = 0; ni < 4; ni++)
                acc[mi][ni] = __builtin_amdgcn_mfma_f32_16x16x32_bf16(af[mi], bfr[ni], acc[mi][ni], 0, 0, 0);
        __syncthreads();
    }

#pragma unroll
    for (int mi = 0; mi < 4; mi++) {
#pragma unroll
        for (int ni = 0; ni < 4; ni++) {
#pragma unroll
            for (int r = 0; r < 4; r++) {
                int row = m0 + wr + mi * 16 + quad * 4 + r;
                int col = n0 + wc + ni * 16 + l16;
                if (row < p.M && col < p.N) {
                    float v = acc[mi][ni][r] * p.alpha;
                    if (p.bias) v += p.bias[col];
                    long idx = (long)row * p.ldc + col;
                    if (p.res) v += p.res[idx];
                    if (p.Cf) p.Cf[idx] = v; else p.Cb[idx] = f2b(v);
                }
            }
        }
    }
}

// ---------------------------------------------------------------------------
// Fused ff1 + GEGLU: H = geglu(A @ W1 + b1). Dual 128x128 tiles per block.
// M, K multiples of 128/32; grid = (2560/128, M/128).
// ---------------------------------------------------------------------------
struct GegluP {
    const u16* A; const u16* Bx; const u16* Bg;
    const float* bx; const float* bg;
    u16* H;
    int K, lda, ldb, ldh;
};

__global__ __launch_bounds__(256) void gemm_geglu(GegluP p) {
    __shared__ u16 As[128 * 32];
    __shared__ u16 Bxs[128 * 32];
    __shared__ u16 Bgs[128 * 32];
    const int tid = threadIdx.x;
    const int m0 = blockIdx.y * 128, n0 = blockIdx.x * 128;
    const int lane = tid & 63, wave = tid >> 6;
    const int quad = lane >> 4, l16 = lane & 15;
    const int wr = (wave >> 1) * 64, wc = (wave & 1) * 64;
    const int srow = lane >> 2, pcb = lane & 3;

    f32x4 ax[4][4], ag[4][4];
#pragma unroll
    for (int i = 0; i < 4; i++)
#pragma unroll
        for (int j = 0; j < 4; j++) { ax[i][j] = (f32x4){0.f,0.f,0.f,0.f}; ag[i][j] = (f32x4){0.f,0.f,0.f,0.f}; }

    for (int k0 = 0; k0 < p.K; k0 += 32) {
#pragma unroll
        for (int j = 0; j < 2; j++) {
            int rbase = wave * 32 + j * 16;
            int r = rbase + srow;
            int lcb = (pcb - (r >> 1)) & 3;
            gld16(p.A  + (long)(m0 + r) * p.lda + k0 + lcb * 8, &As[rbase * 32]);
            gld16(p.Bx + (long)(n0 + r) * p.ldb + k0 + lcb * 8, &Bxs[rbase * 32]);
            gld16(p.Bg + (long)(n0 + r) * p.ldb + k0 + lcb * 8, &Bgs[rbase * 32]);
        }
        __syncthreads();

        bf16x8 af[4], bxf[4], bgf[4];
#pragma unroll
        for (int mi = 0; mi < 4; mi++) {
            int row = wr + mi * 16 + l16;
            af[mi] = *(const bf16x8*)&As[row * 32 + swz(row, quad) * 8];
        }
#pragma unroll
        for (int ni = 0; ni < 4; ni++) {
            int row = wc + ni * 16 + l16;
            bxf[ni] = *(const bf16x8*)&Bxs[row * 32 + swz(row, quad) * 8];
            bgf[ni] = *(const bf16x8*)&Bgs[row * 32 + swz(row, quad) * 8];
        }
#pragma unroll
        for (int mi = 0; mi < 4; mi++)
#pragma unroll
            for (int ni = 0; ni < 4; ni++) {
                ax[mi][ni] = __builtin_amdgcn_mfma_f32_16x16x32_bf16(af[mi], bxf[ni], ax[mi][ni], 0, 0, 0);
                ag[mi][ni] = __builtin_amdgcn_mfma_f32_16x16x32_bf16(af[mi], bgf[ni], ag[mi][ni], 0, 0, 0);
            }
        __syncthreads();
    }

#pragma unroll
    for (int mi = 0; mi < 4; mi++) {
#pragma unroll
        for (int ni = 0; ni < 4; ni++) {
#pragma unroll
            for (int r = 0; r < 4; r++) {
                int row = m0 + wr + mi * 16 + quad * 4 + r;
                int col = wc + ni * 16 + l16;
                float xh = ax[mi][ni][r] + p.bx[n0 + col];
                float g  = ag[mi][ni][r] + p.bg[n0 + col];
                float u  = 0.7978845608f * g * (1.0f + 0.044715f * g * g);
                float s  = 1.0f / (1.0f + __expf(-2.0f * u));
                p.H[(long)row * p.ldh + n0 + col] = f2b(xh * g * s);
            }
        }
    }
}

// ---------------------------------------------------------------------------
// Fused flash attention: one block = (z = b*8+h, 128-row Q tile)
// ---------------------------------------------------------------------------
struct FlashP {
    const u16* Q; const u16* K; const u16* V;
    u16* O;
    int ldq, ldk, ldv, ldo;
    int S, TS, nIter;
    long qBatch, kBatch;
    float scale;
};

__global__ __launch_bounds__(256, 2) void flash_attn(FlashP p) {
    __shared__ u16 shU[128 * 136];
    __shared__ u16 shV[80 * 136];
    const int z = blockIdx.z, b = z >> 3, h = z & 7;
    const int q0 = blockIdx.x * 128;
    const int tid = threadIdx.x, lane = tid & 63, w = tid >> 6;
    const int quad = lane >> 4, l16 = lane & 15;

    const u16* Qp = p.Q + (long)b * p.qBatch + (long)q0 * p.ldq + h * 80;
    const u16* Kp = p.K + (long)b * p.kBatch + h * 80;
    const u16* Vp = p.V + (long)b * p.kBatch + h * 80;

    for (int idx = tid; idx < 128 * 12; idx += 256) {
        int row = idx / 12, g = idx - row * 12;
        uint4 v = {0, 0, 0, 0};
        if (g < 10) v = *(const uint4*)(Qp + (long)row * p.ldq + g * 8);
        *(uint4*)&shU[row * 104 + g * 8] = v;
    }
    __syncthreads();
    bf16x8 qf[2][3];
#pragma unroll
    for (int mi = 0; mi < 2; mi++)
#pragma unroll
        for (int kk = 0; kk < 3; kk++)
            qf[mi][kk] = *(const bf16x8*)&shU[(w * 32 + mi * 16 + l16) * 104 + kk * 32 + quad * 8];
    __syncthreads();

    float m_[2][4], l_[2][4];
    f32x4 acc_o[2][5];
#pragma unroll
    for (int mi = 0; mi < 2; mi++) {
#pragma unroll
        for (int r = 0; r < 4; r++) { m_[mi][r] = -1e30f; l_[mi][r] = 0.f; }
#pragma unroll
        for (int ni = 0; ni < 5; ni++) acc_o[mi][ni] = (f32x4){0.f, 0.f, 0.f, 0.f};
    }

    for (int it = 0; it < p.nIter; it++) {
        const int s0 = it * 128;
        for (int idx = tid; idx < 128 * 12; idx += 256) {
            int row = idx / 12, g = idx - row * 12;
            uint4 v = {0, 0, 0, 0};
            if (g < 10 && (s0 + row) < p.TS)
                v = *(const uint4*)(Kp + (long)(s0 + row) * p.ldk + g * 8);
            *(uint4*)&shU[row * 104 + g * 8] = v;
        }
        for (int idx = tid; idx < 128 * 10; idx += 256) {
            int row = idx / 10, g = idx - row * 10;
            uint4 v = {0, 0, 0, 0};
            if ((s0 + row) < p.TS)
                v = *(const uint4*)(Vp + (long)(s0 + row) * p.ldv + g * 8);
            u16 tmp[8]; *(uint4*)tmp = v;
#pragma unroll
            for (int j = 0; j < 8; j++) shV[(g * 8 + j) * 136 + row] = tmp[j];
        }
        __syncthreads();

        f32x4 acc_s[2][8];
#pragma unroll
        for (int mi = 0; mi < 2; mi++)
#pragma unroll
            for (int ni = 0; ni < 8; ni++) acc_s[mi][ni] = (f32x4){0.f, 0.f, 0.f, 0.f};
#pragma unroll
        for (int kk = 0; kk < 3; kk++) {
            bf16x8 kf[8];
#pragma unroll
            for (int ni = 0; ni < 8; ni++)
                kf[ni] = *(const bf16x8*)&shU[(ni * 16 + l16) * 104 + kk * 32 + quad * 8];
#pragma unroll
            for (int mi = 0; mi < 2; mi++)
#pragma unroll
                for (int ni = 0; ni < 8; ni++)
                    acc_s[mi][ni] = __builtin_amdgcn_mfma_f32_16x16x32_bf16(qf[mi][kk], kf[ni], acc_s[mi][ni], 0, 0, 0);
        }
        __syncthreads();

#pragma unroll
        for (int mi = 0; mi < 2; mi++) {
#pragma unroll
            for (int ni = 0; ni < 8; ni++) {
                bool valid = (s0 + ni * 16 + l16) < p.TS;
#pragma unroll
                for (int r = 0; r < 4; r++)
                    acc_s[mi][ni][r] = valid ? acc_s[mi][ni][r] * p.scale : -1e30f;
            }
#pragma unroll
            for (int r = 0; r < 4; r++) {
                float rm = acc_s[mi][0][r];
#pragma unroll
                for (int ni = 1; ni < 8; ni++) rm = fmaxf(rm, acc_s[mi][ni][r]);
#pragma unroll
                for (int msk = 1; msk < 16; msk <<= 1) rm = fmaxf(rm, __shfl_xor(rm, msk));
                float mn = fmaxf(m_[mi][r], rm);
                float al = __expf(m_[mi][r] - mn);
                m_[mi][r] = mn;
                float rs = 0.f;
                int prow = (w * 32 + mi * 16 + quad * 4 + r) * 136;
#pragma unroll
                for (int ni = 0; ni < 8; ni++) {
                    float pv = __expf(acc_s[mi][ni][r] - mn);
                    rs += pv;
                    shU[prow + ni * 16 + l16] = f2b(pv);
                }
#pragma unroll
                for (int msk = 1; msk < 16; msk <<= 1) rs += __shfl_xor(rs, msk);
                l_[mi][r] = l_[mi][r] * al + rs;
#pragma unroll
                for (int ni = 0; ni < 5; ni++) acc_o[mi][ni][r] *= al;
            }
        }
        __syncthreads();

#pragma unroll
        for (int kk = 0; kk < 4; kk++) {
            bf16x8 vf[5], pf[2];
#pragma unroll
            for (int ni = 0; ni < 5; ni++)
                vf[ni] = *(const bf16x8*)&shV[(ni * 16 + l16) * 136 + kk * 32 + quad * 8];
#pragma unroll
            for (int mi = 0; mi < 2; mi++)
                pf[mi] = *(const bf16x8*)&shU[(w * 32 + mi * 16 + l16) * 136 + kk * 32 + quad * 8];
#pragma unroll
            for (int mi = 0; mi < 2; mi++)
#pragma unroll
                for (int ni = 0; ni < 5; ni++)
                    acc_o[mi][ni] = __builtin_amdgcn_mfma_f32_16x16x32_bf16(pf[mi], vf[ni], acc_o[mi][ni], 0, 0, 0);
        }
        __syncthreads();
    }

    u16* Op = p.O + ((long)b * p.S + q0) * p.ldo + h * 80;
#pragma unroll
    for (int mi = 0; mi < 2; mi++) {
#pragma unroll
        for (int r = 0; r < 4; r++) {
            float inv = 1.0f / l_[mi][r];
            int row = w * 32 + mi * 16 + quad * 4 + r;
#pragma unroll
            for (int ni = 0; ni < 5; ni++)
                Op[(long)row * p.ldo + ni * 16 + l16] = f2b(acc_o[mi][ni][r] * inv);
        }
    }
}

// ---------------------------------------------------------------------------
struct WT8 { const float* W[8]; u16* Wt[8]; };

__global__ void wtrans8(WT8 p, int K, int N) {
    __shared__ float tile[32][33];
    const float* W = p.W[blockIdx.z];
    u16* Wt = p.Wt[blockIdx.z];
    int n0 = blockIdx.x * 32, k0 = blockIdx.y * 32;
    int tx = threadIdx.x, ty = threadIdx.y;
#pragma unroll
    for (int i = 0; i < 4; i++) {
        int k = k0 + ty + i * 8, n = n0 + tx;
        if (k < K && n < N) tile[ty + i * 8][tx] = W[(long)k * N + n];
    }
    __syncthreads();
#pragma unroll
    for (int i = 0; i < 4; i++) {
        int n = n0 + ty + i * 8, k = k0 + tx;
        if (n < N && k < K) Wt[(long)n * K + k] = f2b(tile[tx][ty + i * 8]);
    }
}

// ---------------------------------------------------------------------------
__global__ void gn_stats(const float* __restrict__ x, float* __restrict__ stats) {
    int bid = blockIdx.x;
    int b = bid >> 5, g = bid & 31;
    const float* base = x + (long)b * 32 * 32 * 640 + g * 20;
    float s = 0.f, sq = 0.f;
    for (int idx = threadIdx.x; idx < 32 * 32 * 20; idx += 256) {
        int hw = idx / 20, c = idx - hw * 20;
        float v = base[(long)hw * 640 + c];
        s += v; sq += v * v;
    }
    __shared__ float rs[256], rq[256];
    rs[threadIdx.x] = s; rq[threadIdx.x] = sq; __syncthreads();
    for (int t = 128; t > 0; t >>= 1) {
        if (threadIdx.x < t) { rs[threadIdx.x] += rs[threadIdx.x + t]; rq[threadIdx.x] += rq[threadIdx.x + t]; }
        __syncthreads();
    }
    if (threadIdx.x == 0) {
        float mean = rs[0] / 20480.0f;
        float var = rq[0] / 20480.0f - mean * mean;
        stats[bid * 2] = mean;
        stats[bid * 2 + 1] = rsqrtf(var + 1e-5f);
    }
}

__global__ void gn_apply(const float* __restrict__ x, const float* __restrict__ stats,
                         const float* __restrict__ gamma, const float* __restrict__ beta,
                         u16* __restrict__ out) {
    long i = (long)blockIdx.x * 256 + threadIdx.x;
    int c = (int)(i % 640);
    int b = (int)(i / (32 * 32 * 640));
    int g = c / 20;
    float mean = stats[(b * 32 + g) * 2], inv = stats[(b * 32 + g) * 2 + 1];
    out[i] = f2b((x[i] - mean) * inv * gamma[c] + beta[c]);
}

// ---------------------------------------------------------------------------
__global__ void layernorm_rows(const float* __restrict__ X, const float* __restrict__ g,
                               const float* __restrict__ be, u16* __restrict__ out, int nrows) {
    int row = blockIdx.x * 4 + (threadIdx.x >> 6);
    int lane = threadIdx.x & 63;
    if (row >= nrows) return;
    const float* x = X + (long)row * 640;
    float v[10];
    float s = 0.f;
#pragma unroll
    for (int i = 0; i < 10; i++) { v[i] = x[lane + i * 64]; s += v[i]; }
#pragma unroll
    for (int m = 1; m < 64; m <<= 1) s += __shfl_xor(s, m);
    float mean = s * (1.0f / 640.0f);
    float sq = 0.f;
#pragma unroll
    for (int i = 0; i < 10; i++) { float d = v[i] - mean; sq += d * d; }
#pragma unroll
    for (int m = 1; m < 64; m <<= 1) sq += __shfl_xor(sq, m);
    float inv = rsqrtf(sq * (1.0f / 640.0f) + 1e-5f);
    u16* o = out + (long)row * 640;
#pragma unroll
    for (int i = 0; i < 10; i++) {
        int c = lane + i * 64;
        o[c] = f2b((v[i] - mean) * inv * g[c] + be[c]);
    }
}

// ---------------------------------------------------------------------------
__global__ void f2b_k(const float* __restrict__ src, u16* __restrict__ dst, long n) {
    long i = (long)blockIdx.x * 256 + threadIdx.x;
    if (i < n) dst[i] = f2b(src[i]);
}

// ===========================================================================
extern "C" void kernel_launch(void* const* d_in, const int* in_sizes, int n_in,
                              void* d_out, int out_size, void* d_ws, size_t ws_size,
                              hipStream_t stream) {
    const float* x        = (const float*)d_in[0];
    const float* context  = (const float*)d_in[1];
    const float* gn_gamma = (const float*)d_in[2];
    const float* gn_beta  = (const float*)d_in[3];
    const float* proj_in_w = (const float*)d_in[4];
    const float* proj_in_b = (const float*)d_in[5];
    const float* ln1_g = (const float*)d_in[6];
    const float* ln1_b = (const float*)d_in[7];
    const float* a1_q = (const float*)d_in[8];
    const float* a1_k = (const float*)d_in[9];
    const float* a1_v = (const float*)d_in[10];
    const float* a1_o = (const float*)d_in[11];
    const float* a1_ob = (const float*)d_in[12];
    const float* ln2_g = (const float*)d_in[13];
    const float* ln2_b = (const float*)d_in[14];
    const float* a2_q = (const float*)d_in[15];
    const float* a2_k = (const float*)d_in[16];
    const float* a2_v = (const float*)d_in[17];
    const float* a2_o = (const float*)d_in[18];
    const float* a2_ob = (const float*)d_in[19];
    const float* ln3_g = (const float*)d_in[20];
    const float* ln3_b = (const float*)d_in[21];
    const float* ff1_w = (const float*)d_in[22];
    const float* ff1_b = (const float*)d_in[23];
    const float* ff2_w = (const float*)d_in[24];
    const float* ff2_b = (const float*)d_in[25];
    const float* proj_out_w = (const float*)d_in[26];
    const float* proj_out_b = (const float*)d_in[27];
    float* out = (float*)d_out;

    // ---- workspace carve-up ----
    char* ws = (char*)d_ws;
    size_t off = 0;
    auto alloc = [&](size_t bytes) -> void* {
        void* p = ws + off;
        off += (bytes + 255) & ~(size_t)255;
        return p;
    };
    u16* Wt_pi  = (u16*)alloc(640 * 640 * 2);
    u16* Wt_qkv = (u16*)alloc((size_t)1920 * 640 * 2);
    u16* Wt_1o  = (u16*)alloc(640 * 640 * 2);
    u16* Wt_2q  = (u16*)alloc(640 * 640 * 2);
    u16* Wt_kv2 = (u16*)alloc((size_t)1280 * 768 * 2);
    u16* Wt_2o  = (u16*)alloc(640 * 640 * 2);
    u16* Wt_f1  = (u16*)alloc((size_t)5120 * 640 * 2);
    u16* Wt_f2  = (u16*)alloc((size_t)640 * 2560 * 2);
    u16* Wt_po  = (u16*)alloc(640 * 640 * 2);
    float* t    = (float*)alloc((size_t)8192 * 640 * 4);
    u16* bufA   = (u16*)alloc((size_t)8192 * 640 * 2);
    u16* big    = (u16*)alloc((size_t)8192 * 2560 * 2);  // qkv (8192x1920) / h (8192x2560)
    u16* kv2b   = (u16*)alloc((size_t)616 * 1280 * 2);
    u16* ctxb   = (u16*)alloc((size_t)616 * 768 * 2);
    float* stats = (float*)alloc(256 * 2 * 4);
    (void)alloc(65536);   // guard region: OOB M-tile DMA reads land here
    u16* qkvb = big;
    u16* hb   = big;

    const float SCALE = 0.11180339887498949f;

    auto gemm1 = [&](const u16* A, const float* Af, const u16* Bt, const float* bias,
                     const float* res, float* Cf, u16* Cb, int M, int N, int K,
                     int lda, int ldb, int ldc, float alpha) {
        GemmP p{};
        p.A = A; p.Af = Af; p.B = Bt; p.bias = bias; p.res = res; p.Cf = Cf; p.Cb = Cb;
        p.M = M; p.N = N; p.K = K; p.lda = lda; p.ldb = ldb; p.ldc = ldc;
        p.alpha = alpha;
        dim3 grid((N + 127) / 128, (M + 127) / 128, 1);
        gemm_bt<<<grid, 256, 0, stream>>>(p);
    };

    // ---- 1. weight conversion ----
    {
        dim3 blk(32, 8);
        WT8 sq{};
        sq.W[0] = proj_in_w; sq.Wt[0] = Wt_pi;
        sq.W[1] = a1_q;      sq.Wt[1] = Wt_qkv;
        sq.W[2] = a1_k;      sq.Wt[2] = Wt_qkv + 640 * 640;
        sq.W[3] = a1_v;      sq.Wt[3] = Wt_qkv + 2 * 640 * 640;
        sq.W[4] = a1_o;      sq.Wt[4] = Wt_1o;
        sq.W[5] = a2_q;      sq.Wt[5] = Wt_2q;
        sq.W[6] = a2_o;      sq.Wt[6] = Wt_2o;
        sq.W[7] = proj_out_w; sq.Wt[7] = Wt_po;
        wtrans8<<<dim3(20, 20, 8), blk, 0, stream>>>(sq, 640, 640);
        WT8 kv{};
        kv.W[0] = a2_k; kv.Wt[0] = Wt_kv2;
        kv.W[1] = a2_v; kv.Wt[1] = Wt_kv2 + (size_t)640 * 768;
        wtrans8<<<dim3(20, 24, 2), blk, 0, stream>>>(kv, 768, 640);
        WT8 f1{}; f1.W[0] = ff1_w; f1.Wt[0] = Wt_f1;
        wtrans8<<<dim3(160, 20, 1), blk, 0, stream>>>(f1, 640, 5120);
        WT8 f2{}; f2.W[0] = ff2_w; f2.Wt[0] = Wt_f2;
        wtrans8<<<dim3(20, 80, 1), blk, 0, stream>>>(f2, 2560, 640);
    }

    // ---- 2. GroupNorm + proj_in ----
    gn_stats<<<256, 256, 0, stream>>>(x, stats);
    gn_apply<<<20480, 256, 0, stream>>>(x, stats, gn_gamma, gn_beta, bufA);
    gemm1(bufA, nullptr, Wt_pi, proj_in_b, nullptr, t, nullptr, 8192, 640, 640, 640, 640, 640, 1.0f);

    // ---- 3. self-attention ----
    layernorm_rows<<<2048, 256, 0, stream>>>(t, ln1_g, ln1_b, bufA, 8192);
    gemm1(bufA, nullptr, Wt_qkv, nullptr, nullptr, nullptr, qkvb, 8192, 1920, 640, 640, 640, 1920, 1.0f);
    {
        FlashP p{};
        p.Q = qkvb; p.K = qkvb + 640; p.V = qkvb + 1280; p.O = bufA;
        p.ldq = 1920; p.ldk = 1920; p.ldv = 1920; p.ldo = 640;
        p.S = 1024; p.TS = 1024; p.nIter = 8;
        p.qBatch = (long)1024 * 1920; p.kBatch = (long)1024 * 1920;
        p.scale = SCALE;
        flash_attn<<<dim3(8, 1, 64), 256, 0, stream>>>(p);
    }
    gemm1(bufA, nullptr, Wt_1o, a1_ob, t, t, nullptr, 8192, 640, 640, 640, 640, 640, 1.0f);

    // ---- 4. cross-attention ----
    layernorm_rows<<<2048, 256, 0, stream>>>(t, ln2_g, ln2_b, bufA, 8192);
    f2b_k<<<1848, 256, 0, stream>>>(context, ctxb, 473088);
    gemm1(bufA, nullptr, Wt_2q, nullptr, nullptr, nullptr, qkvb, 8192, 640, 640, 640, 640, 640, 1.0f);
    gemm1(ctxb, nullptr, Wt_kv2, nullptr, nullptr, nullptr, kv2b, 616, 1280, 768, 768, 768, 1280, 1.0f);
    {
        FlashP p{};
        p.Q = qkvb; p.K = kv2b; p.V = kv2b + 640; p.O = bufA;
        p.ldq = 640; p.ldk = 1280; p.ldv = 1280; p.ldo = 640;
        p.S = 1024; p.TS = 77; p.nIter = 1;
        p.qBatch = (long)1024 * 640; p.kBatch = (long)77 * 1280;
        p.scale = SCALE;
        flash_attn<<<dim3(8, 1, 64), 256, 0, stream>>>(p);
    }
    gemm1(bufA, nullptr, Wt_2o, a2_ob, t, t, nullptr, 8192, 640, 640, 640, 640, 640, 1.0f);

    // ---- 5. FFN: fused ff1+GEGLU, then ff2 ----
    layernorm_rows<<<2048, 256, 0, stream>>>(t, ln3_g, ln3_b, bufA, 8192);
    {
        GegluP p{};
        p.A = bufA; p.Bx = Wt_f1; p.Bg = Wt_f1 + (size_t)2560 * 640;
        p.bx = ff1_b; p.bg = ff1_b + 2560;
        p.H = hb;
        p.K = 640; p.lda = 640; p.ldb = 640; p.ldh = 2560;
        gemm_geglu<<<dim3(20, 64), 256, 0, stream>>>(p);
    }
    gemm1(hb, nullptr, Wt_f2, ff2_b, t, t, nullptr, 8192, 640, 2560, 2560, 2560, 640, 1.0f);

    // ---- 6. proj_out + x residual (reads f32 t directly) ----
    gemm1(nullptr, t, Wt_po, proj_out_b, x, out, nullptr, 8192, 640, 640, 640, 640, 640, 1.0f);
}

// Round 5
// 699.651 us; speedup vs baseline: 2.4747x; 1.2178x over previous
//
#include <hip/hip_runtime.h>
#include <hip/hip_bf16.h>
#include <math.h>

typedef unsigned short u16;
typedef unsigned int u32;
typedef __attribute__((ext_vector_type(8))) short bf16x8;
typedef __attribute__((ext_vector_type(4))) float f32x4;

__device__ __forceinline__ u16 f2b(float f) {
    union { float f; unsigned u; } v; v.f = f;
    unsigned r = v.u + 0x7fffu + ((v.u >> 16) & 1u);
    return (u16)(r >> 16);
}
__device__ __forceinline__ float b2f(u16 h) {
    union { unsigned u; float f; } v; v.u = ((unsigned)h) << 16; return v.f;
}

// global -> LDS direct DMA, 16 bytes per lane. LDS dest = uniform base + lane*16.
__device__ __forceinline__ void gld16(const u16* gp, u16* lp) {
    auto g = (const __attribute__((address_space(1))) u32*)gp;
    auto l = (__attribute__((address_space(3))) u32*)lp;
    __builtin_amdgcn_global_load_lds(g, l, 16, 0, 0);
}

// LDS row = 64 u16 = eight 16B blocks (128 B = full bank wrap).
// physical block for logical K-block lb at row r: (lb + (r>>1)) & 7.
__device__ __forceinline__ int swz8(int row, int lb) { return (lb + (row >> 1)) & 7; }

// ---------------------------------------------------------------------------
// Generic bf16 MFMA GEMM:  C = alpha * A @ Bt^T (+bias) (+res)
// A: M x K row-major (lda) bf16, or f32 via Af. Bt: N x K row-major (ldb).
// K % 64 == 0, lda/ldb % 8 == 0. N-tile fixed 128; M-tile = MT (64 or 128).
// OOB M rows may DMA garbage from within ws (store-guarded); keep guard region.
// ---------------------------------------------------------------------------
struct GemmP {
    const u16* A; const float* Af; const u16* B;
    const float* bias; const float* res;
    float* Cf; u16* Cb;
    int M, N, K, lda, ldb, ldc;
    float alpha;
};

template<int MT>
__global__ __launch_bounds__(256) void gemm_bt(GemmP p) {
    constexpr int MI = MT / 32;          // m-frags per wave
    __shared__ u16 As[MT * 64];
    __shared__ u16 Bs[128 * 64];
    const int tid = threadIdx.x;
    const int m0 = blockIdx.y * MT, n0 = blockIdx.x * 128;
    const int lane = tid & 63, wave = tid >> 6;
    const int quad = lane >> 4, l16 = lane & 15;
    const int wr = (wave >> 1) * (MT / 2), wc = (wave & 1) * 64;
    const int srow = lane >> 3, pb8 = lane & 7;

    f32x4 acc[MI][4];
#pragma unroll
    for (int i = 0; i < MI; i++)
#pragma unroll
        for (int j = 0; j < 4; j++) acc[i][j] = (f32x4){0.f, 0.f, 0.f, 0.f};

    for (int k0 = 0; k0 < p.K; k0 += 64) {
        if (p.Af) {
            // A from f32, on-the-fly convert, swizzled register staging
            constexpr int TPR = 256 / MT;          // threads per row
            constexpr int NB = 8 / TPR;            // 16B blocks per thread
            int row = tid / TPR, part = tid % TPR;
            const float* srcr = p.Af + (long)(m0 + row) * p.lda + k0;
#pragma unroll
            for (int q2 = 0; q2 < NB; q2++) {
                int lb = part * NB + q2;
                float4 f0 = *(const float4*)(srcr + lb * 8);
                float4 f1 = *(const float4*)(srcr + lb * 8 + 4);
                u16 tmp[8];
                tmp[0]=f2b(f0.x); tmp[1]=f2b(f0.y); tmp[2]=f2b(f0.z); tmp[3]=f2b(f0.w);
                tmp[4]=f2b(f1.x); tmp[5]=f2b(f1.y); tmp[6]=f2b(f1.z); tmp[7]=f2b(f1.w);
                *(uint4*)&As[row * 64 + swz8(row, lb) * 8] = *(uint4*)tmp;
            }
        } else {
#pragma unroll
            for (int j = 0; j < MT / 32; j++) {
                int rbase = wave * (MT / 4) + j * 8;
                int r = rbase + srow;
                int lb = (pb8 - (r >> 1)) & 7;
                gld16(p.A + (long)(m0 + r) * p.lda + k0 + lb * 8, &As[rbase * 64]);
            }
        }
#pragma unroll
        for (int j = 0; j < 4; j++) {
            int rbase = wave * 32 + j * 8;
            int r = rbase + srow;
            int lb = (pb8 - (r >> 1)) & 7;
            gld16(p.B + (long)(n0 + r) * p.ldb + k0 + lb * 8, &Bs[rbase * 64]);
        }
        __syncthreads();

#pragma unroll
        for (int kk = 0; kk < 2; kk++) {
            bf16x8 af[MI], bfr[4];
#pragma unroll
            for (int mi = 0; mi < MI; mi++) {
                int row = wr + mi * 16 + l16;
                af[mi] = *(const bf16x8*)&As[row * 64 + swz8(row, kk * 4 + quad) * 8];
            }
#pragma unroll
            for (int ni = 0; ni < 4; ni++) {
                int row = wc + ni * 16 + l16;
                bfr[ni] = *(const bf16x8*)&Bs[row * 64 + swz8(row, kk * 4 + quad) * 8];
            }
#pragma unroll
            for (int mi = 0; mi < MI; mi++)
#pragma unroll
                for (int ni = 0; ni < 4; ni++)
                    acc[mi][ni] = __builtin_amdgcn_mfma_f32_16x16x32_bf16(af[mi], bfr[ni], acc[mi][ni], 0, 0, 0);
        }
        __syncthreads();
    }

#pragma unroll
    for (int mi = 0; mi < MI; mi++) {
#pragma unroll
        for (int ni = 0; ni < 4; ni++) {
#pragma unroll
            for (int r = 0; r < 4; r++) {
                int row = m0 + wr + mi * 16 + quad * 4 + r;
                int col = n0 + wc + ni * 16 + l16;
                if (row < p.M && col < p.N) {
                    float v = acc[mi][ni][r] * p.alpha;
                    if (p.bias) v += p.bias[col];
                    long idx = (long)row * p.ldc + col;
                    if (p.res) v += p.res[idx];
                    if (p.Cf) p.Cf[idx] = v; else p.Cb[idx] = f2b(v);
                }
            }
        }
    }
}

// ---------------------------------------------------------------------------
// Fused ff1 + GEGLU: H = geglu(A @ W1 + b1). Dual 128x128 tiles per block.
// M, K multiples of 128/64; grid = (2560/128, M/128).
// ---------------------------------------------------------------------------
struct GegluP {
    const u16* A; const u16* Bx; const u16* Bg;
    const float* bx; const float* bg;
    u16* H;
    int K, lda, ldb, ldh;
};

__global__ __launch_bounds__(256) void gemm_geglu(GegluP p) {
    __shared__ u16 As[128 * 64];
    __shared__ u16 Bxs[128 * 64];
    __shared__ u16 Bgs[128 * 64];
    const int tid = threadIdx.x;
    const int m0 = blockIdx.y * 128, n0 = blockIdx.x * 128;
    const int lane = tid & 63, wave = tid >> 6;
    const int quad = lane >> 4, l16 = lane & 15;
    const int wr = (wave >> 1) * 64, wc = (wave & 1) * 64;
    const int srow = lane >> 3, pb8 = lane & 7;

    f32x4 ax[4][4], ag[4][4];
#pragma unroll
    for (int i = 0; i < 4; i++)
#pragma unroll
        for (int j = 0; j < 4; j++) { ax[i][j] = (f32x4){0.f,0.f,0.f,0.f}; ag[i][j] = (f32x4){0.f,0.f,0.f,0.f}; }

    for (int k0 = 0; k0 < p.K; k0 += 64) {
#pragma unroll
        for (int j = 0; j < 4; j++) {
            int rbase = wave * 32 + j * 8;
            int r = rbase + srow;
            int lb = (pb8 - (r >> 1)) & 7;
            gld16(p.A  + (long)(m0 + r) * p.lda + k0 + lb * 8, &As[rbase * 64]);
            gld16(p.Bx + (long)(n0 + r) * p.ldb + k0 + lb * 8, &Bxs[rbase * 64]);
            gld16(p.Bg + (long)(n0 + r) * p.ldb + k0 + lb * 8, &Bgs[rbase * 64]);
        }
        __syncthreads();

#pragma unroll
        for (int kk = 0; kk < 2; kk++) {
            bf16x8 af[4], bxf[4], bgf[4];
#pragma unroll
            for (int mi = 0; mi < 4; mi++) {
                int row = wr + mi * 16 + l16;
                af[mi] = *(const bf16x8*)&As[row * 64 + swz8(row, kk * 4 + quad) * 8];
            }
#pragma unroll
            for (int ni = 0; ni < 4; ni++) {
                int row = wc + ni * 16 + l16;
                bxf[ni] = *(const bf16x8*)&Bxs[row * 64 + swz8(row, kk * 4 + quad) * 8];
                bgf[ni] = *(const bf16x8*)&Bgs[row * 64 + swz8(row, kk * 4 + quad) * 8];
            }
#pragma unroll
            for (int mi = 0; mi < 4; mi++)
#pragma unroll
                for (int ni = 0; ni < 4; ni++) {
                    ax[mi][ni] = __builtin_amdgcn_mfma_f32_16x16x32_bf16(af[mi], bxf[ni], ax[mi][ni], 0, 0, 0);
                    ag[mi][ni] = __builtin_amdgcn_mfma_f32_16x16x32_bf16(af[mi], bgf[ni], ag[mi][ni], 0, 0, 0);
                }
        }
        __syncthreads();
    }

#pragma unroll
    for (int mi = 0; mi < 4; mi++) {
#pragma unroll
        for (int ni = 0; ni < 4; ni++) {
#pragma unroll
            for (int r = 0; r < 4; r++) {
                int row = m0 + wr + mi * 16 + quad * 4 + r;
                int col = wc + ni * 16 + l16;
                float xh = ax[mi][ni][r] + p.bx[n0 + col];
                float g  = ag[mi][ni][r] + p.bg[n0 + col];
                float u  = 0.7978845608f * g * (1.0f + 0.044715f * g * g);
                float s  = 1.0f / (1.0f + __expf(-2.0f * u));
                p.H[(long)row * p.ldh + n0 + col] = f2b(xh * g * s);
            }
        }
    }
}

// ---------------------------------------------------------------------------
// Fused flash attention. Grid: (64 heads, 1, nQtiles); blockIdx.x = z = b*8+h
// so the q-tile blocks of one head satisfy id % 8 == h -> same XCD -> K/V
// fetched once into that XCD's L2.
// ---------------------------------------------------------------------------
struct FlashP {
    const u16* Q; const u16* K; const u16* V;
    u16* O;
    int ldq, ldk, ldv, ldo;
    int S, TS, nIter;
    long qBatch, kBatch;
    float scale;
};

__global__ __launch_bounds__(256, 2) void flash_attn(FlashP p) {
    __shared__ u16 shU[128 * 136];
    __shared__ u16 shV[80 * 136];
    const int z = blockIdx.x, b = z >> 3, h = z & 7;
    const int q0 = blockIdx.z * 128;
    const int tid = threadIdx.x, lane = tid & 63, w = tid >> 6;
    const int quad = lane >> 4, l16 = lane & 15;

    const u16* Qp = p.Q + (long)b * p.qBatch + (long)q0 * p.ldq + h * 80;
    const u16* Kp = p.K + (long)b * p.kBatch + h * 80;
    const u16* Vp = p.V + (long)b * p.kBatch + h * 80;

    for (int idx = tid; idx < 128 * 12; idx += 256) {
        int row = idx / 12, g = idx - row * 12;
        uint4 v = {0, 0, 0, 0};
        if (g < 10) v = *(const uint4*)(Qp + (long)row * p.ldq + g * 8);
        *(uint4*)&shU[row * 104 + g * 8] = v;
    }
    __syncthreads();
    bf16x8 qf[2][3];
#pragma unroll
    for (int mi = 0; mi < 2; mi++)
#pragma unroll
        for (int kk = 0; kk < 3; kk++)
            qf[mi][kk] = *(const bf16x8*)&shU[(w * 32 + mi * 16 + l16) * 104 + kk * 32 + quad * 8];
    __syncthreads();

    float m_[2][4], l_[2][4];
    f32x4 acc_o[2][5];
#pragma unroll
    for (int mi = 0; mi < 2; mi++) {
#pragma unroll
        for (int r = 0; r < 4; r++) { m_[mi][r] = -1e30f; l_[mi][r] = 0.f; }
#pragma unroll
        for (int ni = 0; ni < 5; ni++) acc_o[mi][ni] = (f32x4){0.f, 0.f, 0.f, 0.f};
    }

    for (int it = 0; it < p.nIter; it++) {
        const int s0 = it * 128;
        for (int idx = tid; idx < 128 * 12; idx += 256) {
            int row = idx / 12, g = idx - row * 12;
            uint4 v = {0, 0, 0, 0};
            if (g < 10 && (s0 + row) < p.TS)
                v = *(const uint4*)(Kp + (long)(s0 + row) * p.ldk + g * 8);
            *(uint4*)&shU[row * 104 + g * 8] = v;
        }
        for (int idx = tid; idx < 128 * 10; idx += 256) {
            int row = idx / 10, g = idx - row * 10;
            uint4 v = {0, 0, 0, 0};
            if ((s0 + row) < p.TS)
                v = *(const uint4*)(Vp + (long)(s0 + row) * p.ldv + g * 8);
            u16 tmp[8]; *(uint4*)tmp = v;
#pragma unroll
            for (int j = 0; j < 8; j++) shV[(g * 8 + j) * 136 + row] = tmp[j];
        }
        __syncthreads();

        f32x4 acc_s[2][8];
#pragma unroll
        for (int mi = 0; mi < 2; mi++)
#pragma unroll
            for (int ni = 0; ni < 8; ni++) acc_s[mi][ni] = (f32x4){0.f, 0.f, 0.f, 0.f};
#pragma unroll
        for (int kk = 0; kk < 3; kk++) {
            bf16x8 kf[8];
#pragma unroll
            for (int ni = 0; ni < 8; ni++)
                kf[ni] = *(const bf16x8*)&shU[(ni * 16 + l16) * 104 + kk * 32 + quad * 8];
#pragma unroll
            for (int mi = 0; mi < 2; mi++)
#pragma unroll
                for (int ni = 0; ni < 8; ni++)
                    acc_s[mi][ni] = __builtin_amdgcn_mfma_f32_16x16x32_bf16(qf[mi][kk], kf[ni], acc_s[mi][ni], 0, 0, 0);
        }
        __syncthreads();

#pragma unroll
        for (int mi = 0; mi < 2; mi++) {
#pragma unroll
            for (int ni = 0; ni < 8; ni++) {
                bool valid = (s0 + ni * 16 + l16) < p.TS;
#pragma unroll
                for (int r = 0; r < 4; r++)
                    acc_s[mi][ni][r] = valid ? acc_s[mi][ni][r] * p.scale : -1e30f;
            }
#pragma unroll
            for (int r = 0; r < 4; r++) {
                float rm = acc_s[mi][0][r];
#pragma unroll
                for (int ni = 1; ni < 8; ni++) rm = fmaxf(rm, acc_s[mi][ni][r]);
#pragma unroll
                for (int msk = 1; msk < 16; msk <<= 1) rm = fmaxf(rm, __shfl_xor(rm, msk));
                float mn = fmaxf(m_[mi][r], rm);
                float al = __expf(m_[mi][r] - mn);
                m_[mi][r] = mn;
                float rs = 0.f;
                int prow = (w * 32 + mi * 16 + quad * 4 + r) * 136;
#pragma unroll
                for (int ni = 0; ni < 8; ni++) {
                    float pv = __expf(acc_s[mi][ni][r] - mn);
                    rs += pv;
                    shU[prow + ni * 16 + l16] = f2b(pv);
                }
#pragma unroll
                for (int msk = 1; msk < 16; msk <<= 1) rs += __shfl_xor(rs, msk);
                l_[mi][r] = l_[mi][r] * al + rs;
#pragma unroll
                for (int ni = 0; ni < 5; ni++) acc_o[mi][ni][r] *= al;
            }
        }
        __syncthreads();

#pragma unroll
        for (int kk = 0; kk < 4; kk++) {
            bf16x8 vf[5], pf[2];
#pragma unroll
            for (int ni = 0; ni < 5; ni++)
                vf[ni] = *(const bf16x8*)&shV[(ni * 16 + l16) * 136 + kk * 32 + quad * 8];
#pragma unroll
            for (int mi = 0; mi < 2; mi++)
                pf[mi] = *(const bf16x8*)&shU[(w * 32 + mi * 16 + l16) * 136 + kk * 32 + quad * 8];
#pragma unroll
            for (int mi = 0; mi < 2; mi++)
#pragma unroll
                for (int ni = 0; ni < 5; ni++)
                    acc_o[mi][ni] = __builtin_amdgcn_mfma_f32_16x16x32_bf16(pf[mi], vf[ni], acc_o[mi][ni], 0, 0, 0);
        }
        __syncthreads();
    }

    u16* Op = p.O + ((long)b * p.S + q0) * p.ldo + h * 80;
#pragma unroll
    for (int mi = 0; mi < 2; mi++) {
#pragma unroll
        for (int r = 0; r < 4; r++) {
            float inv = 1.0f / l_[mi][r];
            int row = w * 32 + mi * 16 + quad * 4 + r;
#pragma unroll
            for (int ni = 0; ni < 5; ni++)
                Op[(long)row * p.ldo + ni * 16 + l16] = f2b(acc_o[mi][ni][r] * inv);
        }
    }
}

// ---------------------------------------------------------------------------
struct WT8 { const float* W[8]; u16* Wt[8]; };

__global__ void wtrans8(WT8 p, int K, int N) {
    __shared__ float tile[32][33];
    const float* W = p.W[blockIdx.z];
    u16* Wt = p.Wt[blockIdx.z];
    int n0 = blockIdx.x * 32, k0 = blockIdx.y * 32;
    int tx = threadIdx.x, ty = threadIdx.y;
#pragma unroll
    for (int i = 0; i < 4; i++) {
        int k = k0 + ty + i * 8, n = n0 + tx;
        if (k < K && n < N) tile[ty + i * 8][tx] = W[(long)k * N + n];
    }
    __syncthreads();
#pragma unroll
    for (int i = 0; i < 4; i++) {
        int n = n0 + ty + i * 8, k = k0 + tx;
        if (n < N && k < K) Wt[(long)n * K + k] = f2b(tile[tx][ty + i * 8]);
    }
}

// ---------------------------------------------------------------------------
__global__ void gn_stats(const float* __restrict__ x, float* __restrict__ stats) {
    int bid = blockIdx.x;
    int b = bid >> 5, g = bid & 31;
    const float* base = x + (long)b * 32 * 32 * 640 + g * 20;
    float s = 0.f, sq = 0.f;
    for (int idx = threadIdx.x; idx < 32 * 32 * 20; idx += 256) {
        int hw = idx / 20, c = idx - hw * 20;
        float v = base[(long)hw * 640 + c];
        s += v; sq += v * v;
    }
    __shared__ float rs[256], rq[256];
    rs[threadIdx.x] = s; rq[threadIdx.x] = sq; __syncthreads();
    for (int t = 128; t > 0; t >>= 1) {
        if (threadIdx.x < t) { rs[threadIdx.x] += rs[threadIdx.x + t]; rq[threadIdx.x] += rq[threadIdx.x + t]; }
        __syncthreads();
    }
    if (threadIdx.x == 0) {
        float mean = rs[0] / 20480.0f;
        float var = rq[0] / 20480.0f - mean * mean;
        stats[bid * 2] = mean;
        stats[bid * 2 + 1] = rsqrtf(var + 1e-5f);
    }
}

__global__ void gn_apply(const float* __restrict__ x, const float* __restrict__ stats,
                         const float* __restrict__ gamma, const float* __restrict__ beta,
                         u16* __restrict__ out) {
    long i = (long)blockIdx.x * 256 + threadIdx.x;
    int c = (int)(i % 640);
    int b = (int)(i / (32 * 32 * 640));
    int g = c / 20;
    float mean = stats[(b * 32 + g) * 2], inv = stats[(b * 32 + g) * 2 + 1];
    out[i] = f2b((x[i] - mean) * inv * gamma[c] + beta[c]);
}

// ---------------------------------------------------------------------------
__global__ void layernorm_rows(const float* __restrict__ X, const float* __restrict__ g,
                               const float* __restrict__ be, u16* __restrict__ out, int nrows) {
    int row = blockIdx.x * 4 + (threadIdx.x >> 6);
    int lane = threadIdx.x & 63;
    if (row >= nrows) return;
    const float* x = X + (long)row * 640;
    float v[10];
    float s = 0.f;
#pragma unroll
    for (int i = 0; i < 10; i++) { v[i] = x[lane + i * 64]; s += v[i]; }
#pragma unroll
    for (int m = 1; m < 64; m <<= 1) s += __shfl_xor(s, m);
    float mean = s * (1.0f / 640.0f);
    float sq = 0.f;
#pragma unroll
    for (int i = 0; i < 10; i++) { float d = v[i] - mean; sq += d * d; }
#pragma unroll
    for (int m = 1; m < 64; m <<= 1) sq += __shfl_xor(sq, m);
    float inv = rsqrtf(sq * (1.0f / 640.0f) + 1e-5f);
    u16* o = out + (long)row * 640;
#pragma unroll
    for (int i = 0; i < 10; i++) {
        int c = lane + i * 64;
        o[c] = f2b((v[i] - mean) * inv * g[c] + be[c]);
    }
}

// ---------------------------------------------------------------------------
__global__ void f2b_k(const float* __restrict__ src, u16* __restrict__ dst, long n) {
    long i = (long)blockIdx.x * 256 + threadIdx.x;
    if (i < n) dst[i] = f2b(src[i]);
}

// ===========================================================================
extern "C" void kernel_launch(void* const* d_in, const int* in_sizes, int n_in,
                              void* d_out, int out_size, void* d_ws, size_t ws_size,
                              hipStream_t stream) {
    const float* x        = (const float*)d_in[0];
    const float* context  = (const float*)d_in[1];
    const float* gn_gamma = (const float*)d_in[2];
    const float* gn_beta  = (const float*)d_in[3];
    const float* proj_in_w = (const float*)d_in[4];
    const float* proj_in_b = (const float*)d_in[5];
    const float* ln1_g = (const float*)d_in[6];
    const float* ln1_b = (const float*)d_in[7];
    const float* a1_q = (const float*)d_in[8];
    const float* a1_k = (const float*)d_in[9];
    const float* a1_v = (const float*)d_in[10];
    const float* a1_o = (const float*)d_in[11];
    const float* a1_ob = (const float*)d_in[12];
    const float* ln2_g = (const float*)d_in[13];
    const float* ln2_b = (const float*)d_in[14];
    const float* a2_q = (const float*)d_in[15];
    const float* a2_k = (const float*)d_in[16];
    const float* a2_v = (const float*)d_in[17];
    const float* a2_o = (const float*)d_in[18];
    const float* a2_ob = (const float*)d_in[19];
    const float* ln3_g = (const float*)d_in[20];
    const float* ln3_b = (const float*)d_in[21];
    const float* ff1_w = (const float*)d_in[22];
    const float* ff1_b = (const float*)d_in[23];
    const float* ff2_w = (const float*)d_in[24];
    const float* ff2_b = (const float*)d_in[25];
    const float* proj_out_w = (const float*)d_in[26];
    const float* proj_out_b = (const float*)d_in[27];
    float* out = (float*)d_out;

    // ---- workspace carve-up ----
    char* ws = (char*)d_ws;
    size_t off = 0;
    auto alloc = [&](size_t bytes) -> void* {
        void* p = ws + off;
        off += (bytes + 255) & ~(size_t)255;
        return p;
    };
    u16* Wt_pi  = (u16*)alloc(640 * 640 * 2);
    u16* Wt_qkv = (u16*)alloc((size_t)1920 * 640 * 2);
    u16* Wt_1o  = (u16*)alloc(640 * 640 * 2);
    u16* Wt_2q  = (u16*)alloc(640 * 640 * 2);
    u16* Wt_kv2 = (u16*)alloc((size_t)1280 * 768 * 2);
    u16* Wt_2o  = (u16*)alloc(640 * 640 * 2);
    u16* Wt_f1  = (u16*)alloc((size_t)5120 * 640 * 2);
    u16* Wt_f2  = (u16*)alloc((size_t)640 * 2560 * 2);
    u16* Wt_po  = (u16*)alloc(640 * 640 * 2);
    float* t    = (float*)alloc((size_t)8192 * 640 * 4);
    u16* bufA   = (u16*)alloc((size_t)8192 * 640 * 2);
    u16* big    = (u16*)alloc((size_t)8192 * 2560 * 2);  // qkv (8192x1920) / h (8192x2560)
    u16* kv2b   = (u16*)alloc((size_t)616 * 1280 * 2);
    u16* ctxb   = (u16*)alloc((size_t)616 * 768 * 2);
    float* stats = (float*)alloc(256 * 2 * 4);
    (void)alloc(65536);   // guard region: OOB M-tile DMA reads land here
    u16* qkvb = big;
    u16* hb   = big;

    const float SCALE = 0.11180339887498949f;

    auto gemm1 = [&](const u16* A, const float* Af, const u16* Bt, const float* bias,
                     const float* res, float* Cf, u16* Cb, int M, int N, int K,
                     int lda, int ldb, int ldc, float alpha, int mt) {
        GemmP p{};
        p.A = A; p.Af = Af; p.B = Bt; p.bias = bias; p.res = res; p.Cf = Cf; p.Cb = Cb;
        p.M = M; p.N = N; p.K = K; p.lda = lda; p.ldb = ldb; p.ldc = ldc;
        p.alpha = alpha;
        dim3 grid((N + 127) / 128, (M + mt - 1) / mt, 1);
        if (mt == 64) gemm_bt<64><<<grid, 256, 0, stream>>>(p);
        else          gemm_bt<128><<<grid, 256, 0, stream>>>(p);
    };

    // ---- 1. weight conversion ----
    {
        dim3 blk(32, 8);
        WT8 sq{};
        sq.W[0] = proj_in_w; sq.Wt[0] = Wt_pi;
        sq.W[1] = a1_q;      sq.Wt[1] = Wt_qkv;
        sq.W[2] = a1_k;      sq.Wt[2] = Wt_qkv + 640 * 640;
        sq.W[3] = a1_v;      sq.Wt[3] = Wt_qkv + 2 * 640 * 640;
        sq.W[4] = a1_o;      sq.Wt[4] = Wt_1o;
        sq.W[5] = a2_q;      sq.Wt[5] = Wt_2q;
        sq.W[6] = a2_o;      sq.Wt[6] = Wt_2o;
        sq.W[7] = proj_out_w; sq.Wt[7] = Wt_po;
        wtrans8<<<dim3(20, 20, 8), blk, 0, stream>>>(sq, 640, 640);
        WT8 kv{};
        kv.W[0] = a2_k; kv.Wt[0] = Wt_kv2;
        kv.W[1] = a2_v; kv.Wt[1] = Wt_kv2 + (size_t)640 * 768;
        wtrans8<<<dim3(20, 24, 2), blk, 0, stream>>>(kv, 768, 640);
        WT8 f1{}; f1.W[0] = ff1_w; f1.Wt[0] = Wt_f1;
        wtrans8<<<dim3(160, 20, 1), blk, 0, stream>>>(f1, 640, 5120);
        WT8 f2{}; f2.W[0] = ff2_w; f2.Wt[0] = Wt_f2;
        wtrans8<<<dim3(20, 80, 1), blk, 0, stream>>>(f2, 2560, 640);
    }

    // ---- 2. GroupNorm + proj_in ----
    gn_stats<<<256, 256, 0, stream>>>(x, stats);
    gn_apply<<<20480, 256, 0, stream>>>(x, stats, gn_gamma, gn_beta, bufA);
    gemm1(bufA, nullptr, Wt_pi, proj_in_b, nullptr, t, nullptr, 8192, 640, 640, 640, 640, 640, 1.0f, 64);

    // ---- 3. self-attention ----
    layernorm_rows<<<2048, 256, 0, stream>>>(t, ln1_g, ln1_b, bufA, 8192);
    gemm1(bufA, nullptr, Wt_qkv, nullptr, nullptr, nullptr, qkvb, 8192, 1920, 640, 640, 640, 1920, 1.0f, 128);
    {
        FlashP p{};
        p.Q = qkvb; p.K = qkvb + 640; p.V = qkvb + 1280; p.O = bufA;
        p.ldq = 1920; p.ldk = 1920; p.ldv = 1920; p.ldo = 640;
        p.S = 1024; p.TS = 1024; p.nIter = 8;
        p.qBatch = (long)1024 * 1920; p.kBatch = (long)1024 * 1920;
        p.scale = SCALE;
        flash_attn<<<dim3(64, 1, 8), 256, 0, stream>>>(p);
    }
    gemm1(bufA, nullptr, Wt_1o, a1_ob, t, t, nullptr, 8192, 640, 640, 640, 640, 640, 1.0f, 64);

    // ---- 4. cross-attention ----
    layernorm_rows<<<2048, 256, 0, stream>>>(t, ln2_g, ln2_b, bufA, 8192);
    f2b_k<<<1848, 256, 0, stream>>>(context, ctxb, 473088);
    gemm1(bufA, nullptr, Wt_2q, nullptr, nullptr, nullptr, qkvb, 8192, 640, 640, 640, 640, 640, 1.0f, 64);
    gemm1(ctxb, nullptr, Wt_kv2, nullptr, nullptr, nullptr, kv2b, 616, 1280, 768, 768, 768, 1280, 1.0f, 64);
    {
        FlashP p{};
        p.Q = qkvb; p.K = kv2b; p.V = kv2b + 640; p.O = bufA;
        p.ldq = 640; p.ldk = 1280; p.ldv = 1280; p.ldo = 640;
        p.S = 1024; p.TS = 77; p.nIter = 1;
        p.qBatch = (long)1024 * 640; p.kBatch = (long)77 * 1280;
        p.scale = SCALE;
        flash_attn<<<dim3(64, 1, 8), 256, 0, stream>>>(p);
    }
    gemm1(bufA, nullptr, Wt_2o, a2_ob, t, t, nullptr, 8192, 640, 640, 640, 640, 640, 1.0f, 64);

    // ---- 5. FFN: fused ff1+GEGLU, then ff2 ----
    layernorm_rows<<<2048, 256, 0, stream>>>(t, ln3_g, ln3_b, bufA, 8192);
    {
        GegluP p{};
        p.A = bufA; p.Bx = Wt_f1; p.Bg = Wt_f1 + (size_t)2560 * 640;
        p.bx = ff1_b; p.bg = ff1_b + 2560;
        p.H = hb;
        p.K = 640; p.lda = 640; p.ldb = 640; p.ldh = 2560;
        gemm_geglu<<<dim3(20, 64), 256, 0, stream>>>(p);
    }
    gemm1(hb, nullptr, Wt_f2, ff2_b, t, t, nullptr, 8192, 640, 2560, 2560, 2560, 640, 1.0f, 64);

    // ---- 6. proj_out + x residual (reads f32 t directly) ----
    gemm1(nullptr, t, Wt_po, proj_out_b, x, out, nullptr, 8192, 640, 640, 640, 640, 640, 1.0f, 64);
}